// Round 2
// baseline (5234.311 us; speedup 1.0000x reference)
//
#include <hip/hip_runtime.h>
#include <hip/hip_bf16.h>

#define N 2048
#define TILE 32
#define NT 64                  // N / TILE
#define NPAIRS (NT*(NT+1)/2)   // 2080

// ws float offsets
#define OFF_ROWSUM 0
#define OFF_COLSUM 32768
#define OFF_DIAG   65536
#define OFF_SUMS   98304      // [0..15]=diagsum, [16..31]=totsum
#define OFF_A      98336
#define OFF_B      131104
#define OFF_D      163872
#define OFF_C      196640
#define OFF_COLPART 196656    // 64 slabs * 16 c * 2048
#define NSLAB 64

// ---------------- reduce: rowsum, diag, colpart, diagsum/totsum ----------------
__global__ __launch_bounds__(256) void reduce_kernel(const float* __restrict__ X,
                                                     float* __restrict__ ws) {
    const int c = blockIdx.y;
    const int slab = blockIdx.x;          // 64 slabs of 32 rows
    const int tid = threadIdx.x;
    const int wave = tid >> 6, lane = tid & 63;

    float* rowsum = ws + OFF_ROWSUM;
    float* diagv  = ws + OFF_DIAG;
    float* sums   = ws + OFF_SUMS;
    float* colpart = ws + OFF_COLPART + (size_t)slab * 16 * N + (size_t)c * N;

    __shared__ float4 colbuf[4][512];

    float4 colacc[8];
    #pragma unroll
    for (int j = 0; j < 8; ++j) colacc[j] = make_float4(0.f, 0.f, 0.f, 0.f);
    float dacc = 0.f, totacc = 0.f;

    const int row0 = slab * 32 + wave * 8;
    const float* Xc = X + (size_t)c * N * N;
    for (int r = 0; r < 8; ++r) {
        const int row = row0 + r;
        const float4* rp = (const float4*)(Xc + (size_t)row * N);
        float part = 0.f;
        #pragma unroll
        for (int j = 0; j < 8; ++j) {
            const float4 v = rp[lane + 64 * j];
            part += (v.x + v.y) + (v.z + v.w);
            colacc[j].x += v.x; colacc[j].y += v.y;
            colacc[j].z += v.z; colacc[j].w += v.w;
            if (lane + 64 * j == (row >> 2)) {
                const int m = row & 3;
                const float dv = (m == 0) ? v.x : (m == 1) ? v.y : (m == 2) ? v.z : v.w;
                diagv[c * N + row] = dv;
                dacc += dv;
            }
        }
        #pragma unroll
        for (int s = 1; s < 64; s <<= 1) part += __shfl_xor(part, s);
        if (lane == 0) { rowsum[c * N + row] = part; totacc += part; }
    }
    #pragma unroll
    for (int s = 1; s < 64; s <<= 1) dacc += __shfl_xor(dacc, s);
    if (lane == 0) {
        atomicAdd(&sums[c], dacc);
        atomicAdd(&sums[16 + c], totacc);
    }

    // cross-wave column combine via LDS
    #pragma unroll
    for (int j = 0; j < 8; ++j) colbuf[wave][lane + 64 * j] = colacc[j];
    __syncthreads();
    #pragma unroll
    for (int j = 0; j < 2; ++j) {
        const int idx = tid + 256 * j;   // 0..511 float4 slots
        float4 s = colbuf[0][idx];
        const float4 s1 = colbuf[1][idx], s2 = colbuf[2][idx], s3 = colbuf[3][idx];
        s.x += s1.x + s2.x + s3.x; s.y += s1.y + s2.y + s3.y;
        s.z += s1.z + s2.z + s3.z; s.w += s1.w + s2.w + s3.w;
        ((float4*)colpart)[idx] = s;
    }
}

// ---------------- colreduce: colsum[c][y] = sum over slabs ----------------
__global__ __launch_bounds__(256) void colreduce_kernel(float* __restrict__ ws) {
    const int c = blockIdx.y;
    const int y = blockIdx.x * 256 + threadIdx.x;
    const float* colpart = ws + OFF_COLPART;
    float s = 0.f;
    for (int sl = 0; sl < NSLAB; ++sl)
        s += colpart[(size_t)sl * 16 * N + (size_t)c * N + y];
    ws[OFF_COLSUM + c * N + y] = s;
}

// ---------------- fold: A, B, D, C ----------------
__global__ __launch_bounds__(256) void fold_kernel(const float* __restrict__ W,
                                                   const float* __restrict__ bias,
                                                   float* __restrict__ ws) {
    const int o = blockIdx.y;
    const int x = blockIdx.x * 256 + threadIdx.x;
    const float invN = 1.f / (float)N;
    const float invN2 = invN * invN;
    const float* rowsum = ws + OFF_ROWSUM;
    const float* colsum = ws + OFF_COLSUM;
    const float* diagv  = ws + OFF_DIAG;
    const float* sums   = ws + OFF_SUMS;
    float* Abuf = ws + OFF_A;
    float* Bbuf = ws + OFF_B;
    float* Dbuf = ws + OFF_D;
    float* Cbuf = ws + OFF_C;

    if (blockIdx.x == 0 && threadIdx.x == 0) {
        float cacc = 0.f;
        #pragma unroll
        for (int c = 0; c < 16; ++c)
            cacc += (sums[c] * invN) * W[11 * 256 + c * 16 + o]
                  + (sums[16 + c] * invN2) * W[14 * 256 + c * 16 + o];
        float sb = 0.f;
        for (int p = 0; p < 15; ++p) sb += bias[p];
        Cbuf[o] = cacc + sb;
    }

    // uniform part of D (diagmean, totmean terms)
    float du = 0.f;
    #pragma unroll
    for (int c = 0; c < 16; ++c)
        du += (sums[c] * invN) * W[2 * 256 + c * 16 + o]
            + (sums[16 + c] * invN2) * W[4 * 256 + c * 16 + o];

    float a = 0.f, b = 0.f, d = 0.f;
    #pragma unroll
    for (int c = 0; c < 16; ++c) {
        const float dg = diagv[c * N + x];
        const float rm = rowsum[c * N + x] * invN;
        const float cm = colsum[c * N + x] * invN;
        a += dg * W[5 * 256 + c * 16 + o] + rm * W[12 * 256 + c * 16 + o] + cm * W[7 * 256 + c * 16 + o];
        b += dg * W[9 * 256 + c * 16 + o] + rm * W[13 * 256 + c * 16 + o] + cm * W[10 * 256 + c * 16 + o];
        d += dg * W[0 * 256 + c * 16 + o] + rm * W[3 * 256 + c * 16 + o]  + cm * W[1 * 256 + c * 16 + o];
    }
    Abuf[o * N + x] = a;
    Bbuf[o * N + x] = b;
    Dbuf[o * N + x] = d + du;
}

// ---------------- main: tile-pair kernel ----------------
// 1024 threads: og = tid>>9 (o-group of 8), side = (tid>>8)&1, t = tid&255 (4 px each)
__global__ __launch_bounds__(1024, 2) void main_kernel(const float* __restrict__ X,
                                                       const float* __restrict__ W,
                                                       const float* __restrict__ ws,
                                                       float* __restrict__ out) {
    // decode triangular pair (bx <= by)
    int rem = blockIdx.x, bx = 0;
    while (rem >= NT - bx) { rem -= NT - bx; ++bx; }
    const int by = bx + rem;
    const int x0 = bx * TILE, y0 = by * TILE;

    const int tid = threadIdx.x;
    const int og   = tid >> 9;          // o-group: outputs og*8 .. og*8+7
    const int side = (tid >> 8) & 1;    // pixel tile
    const int t    = tid & 255;

    __shared__ float lds[2][4][TILE][TILE + 1];
    __shared__ float wlds[2][16][16];   // [0]=identity (p8), [1]=transpose (p6)

    // stage weights once
    if (tid < 512) {
        const int p = tid >> 8;
        const int r = tid & 255;
        wlds[p][r >> 4][r & 15] = W[(p == 0 ? 8 : 6) * 256 + r];
    }

    const float* Abuf = ws + OFF_A;
    const float* Bbuf = ws + OFF_B;
    const float* Dbuf = ws + OFF_D;
    const float* Cbuf = ws + OFF_C;

    float acc[4][8];
    #pragma unroll
    for (int k = 0; k < 4; ++k)
        #pragma unroll
        for (int oo = 0; oo < 8; ++oo) acc[k][oo] = 0.f;

    // per-pixel LDS offsets (channel stride = 32*33)
    int doff[4], toff[4];
    #pragma unroll
    for (int k = 0; k < 4; ++k) {
        const int px = t + 256 * k;
        const int lx = px >> 5, ly = px & 31;
        doff[k] = lx * (TILE + 1) + ly;
        toff[k] = ly * (TILE + 1) + lx;
    }
    const float* dbase = &lds[side][0][0][0];
    const float* tbase = &lds[1 - side][0][0][0];

    // staging addresses: q = tid + 1024*k → tile k, cl=(tid>>8)&3, row=(tid>>3)&31, qc=tid&7
    const int scl  = (tid >> 8) & 3;
    const int srow = (tid >> 3) & 31;
    const int sqc  = tid & 7;
    const float* gsrc0 = X + (size_t)scl * N * N + (size_t)(x0 + srow) * N + (y0 + 4 * sqc);
    const float* gsrc1 = X + (size_t)scl * N * N + (size_t)(y0 + srow) * N + (x0 + 4 * sqc);
    float* ldst0 = &lds[0][scl][srow][4 * sqc];
    float* ldst1 = &lds[1][scl][srow][4 * sqc];
    const size_t cstep = (size_t)4 * N * N;

    float4 v0 = *(const float4*)gsrc0;
    float4 v1 = *(const float4*)gsrc1;

    for (int cc = 0; cc < 4; ++cc) {
        __syncthreads();   // previous round's reads (and weight staging) done
        ldst0[0] = v0.x; ldst0[1] = v0.y; ldst0[2] = v0.z; ldst0[3] = v0.w;
        ldst1[0] = v1.x; ldst1[1] = v1.y; ldst1[2] = v1.z; ldst1[3] = v1.w;
        __syncthreads();
        if (cc < 3) {      // prefetch next round, overlaps compute below
            gsrc0 += cstep; gsrc1 += cstep;
            v0 = *(const float4*)gsrc0;
            v1 = *(const float4*)gsrc1;
        }

        #pragma unroll
        for (int cl = 0; cl < 4; ++cl) {
            const int c = cc * 4 + cl;
            float dval[4], tval[4];
            #pragma unroll
            for (int k = 0; k < 4; ++k) {
                dval[k] = dbase[cl * (TILE * (TILE + 1)) + doff[k]];
                tval[k] = tbase[cl * (TILE * (TILE + 1)) + toff[k]];
            }
            const float* wi = &wlds[0][c][og * 8];
            const float* wt = &wlds[1][c][og * 8];
            #pragma unroll
            for (int oo = 0; oo < 8; ++oo) {
                const float a = wi[oo], b = wt[oo];
                #pragma unroll
                for (int k = 0; k < 4; ++k) acc[k][oo] += a * dval[k] + b * tval[k];
            }
        }
    }

    // epilogue
    #pragma unroll
    for (int k = 0; k < 4; ++k) {
        const int px = t + 256 * k;
        const int lx = px >> 5, ly = px & 31;
        const int x = (side == 0) ? (x0 + lx) : (y0 + lx);
        const int y = (side == 0) ? (y0 + ly) : (x0 + ly);
        #pragma unroll
        for (int oo = 0; oo < 8; ++oo) {
            const int o = og * 8 + oo;
            float v = acc[k][oo] + Abuf[o * N + x] + Bbuf[o * N + y] + Cbuf[o];
            if (x == y) v += Dbuf[o * N + x];
            __builtin_nontemporal_store(v, &out[(size_t)o * N * N + (size_t)x * N + y]);
        }
    }
}

extern "C" void kernel_launch(void* const* d_in, const int* in_sizes, int n_in,
                              void* d_out, int out_size, void* d_ws, size_t ws_size,
                              hipStream_t stream) {
    (void)in_sizes; (void)n_in; (void)out_size; (void)ws_size;
    const float* X    = (const float*)d_in[0];
    const float* W    = (const float*)d_in[1];
    const float* bias = (const float*)d_in[2];
    float* out = (float*)d_out;
    float* ws  = (float*)d_ws;

    hipMemsetAsync(ws + OFF_SUMS, 0, 32 * sizeof(float), stream);
    reduce_kernel<<<dim3(NSLAB, 16), 256, 0, stream>>>(X, ws);
    colreduce_kernel<<<dim3(8, 16), 256, 0, stream>>>(ws);
    fold_kernel<<<dim3(8, 16), 256, 0, stream>>>(W, bias, ws);
    main_kernel<<<NPAIRS, 1024, 0, stream>>>(X, W, ws, out);
}

// Round 4
// 3033.138 us; speedup vs baseline: 1.7257x; 1.7257x over previous
//
#include <hip/hip_runtime.h>
#include <hip/hip_bf16.h>

#define N 2048
#define TILE 32
#define LSTR 36                // LDS row stride (floats): 16B-aligned quads, bank-shift per row
#define NT 64                  // N / TILE
#define NPAIRS (NT*(NT+1)/2)   // 2080

typedef float f4 __attribute__((ext_vector_type(4)));

// ws float offsets
#define OFF_ROWSUM 0
#define OFF_COLSUM 32768
#define OFF_DIAG   65536
#define OFF_SUMS   98304      // [0..15]=diagsum, [16..31]=totsum
#define OFF_A      98336
#define OFF_B      131104
#define OFF_D      163872
#define OFF_C      196640
#define OFF_COLPART 196656    // 64 slabs * 16 c * 2048
#define NSLAB 64

// ---------------- reduce: rowsum, diag, colpart, diagsum/totsum ----------------
__global__ __launch_bounds__(256) void reduce_kernel(const float* __restrict__ X,
                                                     float* __restrict__ ws) {
    const int c = blockIdx.y;
    const int slab = blockIdx.x;          // 64 slabs of 32 rows
    const int tid = threadIdx.x;
    const int wave = tid >> 6, lane = tid & 63;

    float* rowsum = ws + OFF_ROWSUM;
    float* diagv  = ws + OFF_DIAG;
    float* sums   = ws + OFF_SUMS;
    float* colpart = ws + OFF_COLPART + (size_t)slab * 16 * N + (size_t)c * N;

    __shared__ float4 colbuf[4][512];

    float4 colacc[8];
    #pragma unroll
    for (int j = 0; j < 8; ++j) colacc[j] = make_float4(0.f, 0.f, 0.f, 0.f);
    float dacc = 0.f, totacc = 0.f;

    const int row0 = slab * 32 + wave * 8;
    const float* Xc = X + (size_t)c * N * N;
    for (int r = 0; r < 8; ++r) {
        const int row = row0 + r;
        const float4* rp = (const float4*)(Xc + (size_t)row * N);
        float part = 0.f;
        #pragma unroll
        for (int j = 0; j < 8; ++j) {
            const float4 v = rp[lane + 64 * j];
            part += (v.x + v.y) + (v.z + v.w);
            colacc[j].x += v.x; colacc[j].y += v.y;
            colacc[j].z += v.z; colacc[j].w += v.w;
            if (lane + 64 * j == (row >> 2)) {
                const int m = row & 3;
                const float dv = (m == 0) ? v.x : (m == 1) ? v.y : (m == 2) ? v.z : v.w;
                diagv[c * N + row] = dv;
                dacc += dv;
            }
        }
        #pragma unroll
        for (int s = 1; s < 64; s <<= 1) part += __shfl_xor(part, s);
        if (lane == 0) { rowsum[c * N + row] = part; totacc += part; }
    }
    #pragma unroll
    for (int s = 1; s < 64; s <<= 1) dacc += __shfl_xor(dacc, s);
    if (lane == 0) {
        atomicAdd(&sums[c], dacc);
        atomicAdd(&sums[16 + c], totacc);
    }

    // cross-wave column combine via LDS
    #pragma unroll
    for (int j = 0; j < 8; ++j) colbuf[wave][lane + 64 * j] = colacc[j];
    __syncthreads();
    #pragma unroll
    for (int j = 0; j < 2; ++j) {
        const int idx = tid + 256 * j;   // 0..511 float4 slots
        float4 s = colbuf[0][idx];
        const float4 s1 = colbuf[1][idx], s2 = colbuf[2][idx], s3 = colbuf[3][idx];
        s.x += s1.x + s2.x + s3.x; s.y += s1.y + s2.y + s3.y;
        s.z += s1.z + s2.z + s3.z; s.w += s1.w + s2.w + s3.w;
        ((float4*)colpart)[idx] = s;
    }
}

// ---------------- colreduce: colsum[c][y] = sum over slabs ----------------
__global__ __launch_bounds__(256) void colreduce_kernel(float* __restrict__ ws) {
    const int c = blockIdx.y;
    const int y = blockIdx.x * 256 + threadIdx.x;
    const float* colpart = ws + OFF_COLPART;
    float s = 0.f;
    for (int sl = 0; sl < NSLAB; ++sl)
        s += colpart[(size_t)sl * 16 * N + (size_t)c * N + y];
    ws[OFF_COLSUM + c * N + y] = s;
}

// ---------------- fold: A, B, D, C ----------------
__global__ __launch_bounds__(256) void fold_kernel(const float* __restrict__ W,
                                                   const float* __restrict__ bias,
                                                   float* __restrict__ ws) {
    const int o = blockIdx.y;
    const int x = blockIdx.x * 256 + threadIdx.x;
    const float invN = 1.f / (float)N;
    const float invN2 = invN * invN;
    const float* rowsum = ws + OFF_ROWSUM;
    const float* colsum = ws + OFF_COLSUM;
    const float* diagv  = ws + OFF_DIAG;
    const float* sums   = ws + OFF_SUMS;
    float* Abuf = ws + OFF_A;
    float* Bbuf = ws + OFF_B;
    float* Dbuf = ws + OFF_D;
    float* Cbuf = ws + OFF_C;

    if (blockIdx.x == 0 && threadIdx.x == 0) {
        float cacc = 0.f;
        #pragma unroll
        for (int c = 0; c < 16; ++c)
            cacc += (sums[c] * invN) * W[11 * 256 + c * 16 + o]
                  + (sums[16 + c] * invN2) * W[14 * 256 + c * 16 + o];
        float sb = 0.f;
        for (int p = 0; p < 15; ++p) sb += bias[p];
        Cbuf[o] = cacc + sb;
    }

    // uniform part of D (diagmean, totmean terms)
    float du = 0.f;
    #pragma unroll
    for (int c = 0; c < 16; ++c)
        du += (sums[c] * invN) * W[2 * 256 + c * 16 + o]
            + (sums[16 + c] * invN2) * W[4 * 256 + c * 16 + o];

    float a = 0.f, b = 0.f, d = 0.f;
    #pragma unroll
    for (int c = 0; c < 16; ++c) {
        const float dg = diagv[c * N + x];
        const float rm = rowsum[c * N + x] * invN;
        const float cm = colsum[c * N + x] * invN;
        a += dg * W[5 * 256 + c * 16 + o] + rm * W[12 * 256 + c * 16 + o] + cm * W[7 * 256 + c * 16 + o];
        b += dg * W[9 * 256 + c * 16 + o] + rm * W[13 * 256 + c * 16 + o] + cm * W[10 * 256 + c * 16 + o];
        d += dg * W[0 * 256 + c * 16 + o] + rm * W[3 * 256 + c * 16 + o]  + cm * W[1 * 256 + c * 16 + o];
    }
    Abuf[o * N + x] = a;
    Bbuf[o * N + x] = b;
    Dbuf[o * N + x] = d + du;
}

// ---------------- main: tile-pair kernel ----------------
// 1024 threads: og = tid>>9 (o-group of 8), side = (tid>>8)&1, t = tid&255.
// Each thread owns 4 consecutive-y pixels: lx = t>>3, ly = 4*(t&7)+k.
// NOTE: block = 16 waves = 4 waves/EU -> only 1 block/CU is possible, so do NOT
// declare a min-waves bound; bare launch_bounds caps VGPR at 128 (64 cap spilled
// acc to scratch in the previous round: 16.5 GB of HBM scratch traffic).
__global__ __launch_bounds__(1024) void main_kernel(const float* __restrict__ X,
                                                    const float* __restrict__ W,
                                                    const float* __restrict__ ws,
                                                    float* __restrict__ out) {
    // decode triangular pair (bx <= by)
    int rem = blockIdx.x, bx = 0;
    while (rem >= NT - bx) { rem -= NT - bx; ++bx; }
    const int by = bx + rem;
    const int x0 = bx * TILE, y0 = by * TILE;

    const int tid = threadIdx.x;
    const int og   = tid >> 9;          // o-group: outputs og*8 .. og*8+7
    const int side = (tid >> 8) & 1;    // pixel tile
    const int t    = tid & 255;

    __shared__ float lds[2][4][TILE][LSTR];
    __shared__ float wlds[2][16][16];   // [0]=identity (p8), [1]=transpose (p6)

    // stage weights once
    if (tid < 512) {
        const int p = tid >> 8;
        const int r = tid & 255;
        wlds[p][r >> 4][r & 15] = W[(p == 0 ? 8 : 6) * 256 + r];
    }

    const float* Abuf = ws + OFF_A;
    const float* Bbuf = ws + OFF_B;
    const float* Dbuf = ws + OFF_D;
    const float* Cbuf = ws + OFF_C;

    float acc[4][8];
    #pragma unroll
    for (int k = 0; k < 4; ++k)
        #pragma unroll
        for (int oo = 0; oo < 8; ++oo) acc[k][oo] = 0.f;

    // per-thread pixel geometry
    const int lx  = t >> 3;          // 0..31
    const int ly0 = 4 * (t & 7);     // 0,4,...,28
    const int doff = lx * LSTR + ly0;            // direct: 4 consecutive floats
    const int toff = ly0 * LSTR + lx;            // transpose: stride LSTR
    const float* dbase = &lds[side][0][0][0];
    const float* tbase = &lds[1 - side][0][0][0];

    // staging: tid = (ch<<8)|(row<<3)|qc
    const int scl  = (tid >> 8) & 3;
    const int srow = (tid >> 3) & 31;
    const int sqc  = tid & 7;
    const float* gsrc0 = X + (size_t)scl * N * N + (size_t)(x0 + srow) * N + (y0 + 4 * sqc);
    const float* gsrc1 = X + (size_t)scl * N * N + (size_t)(y0 + srow) * N + (x0 + 4 * sqc);
    float* ldst0 = &lds[0][scl][srow][4 * sqc];
    float* ldst1 = &lds[1][scl][srow][4 * sqc];
    const size_t cstep = (size_t)4 * N * N;

    f4 v0 = *(const f4*)gsrc0;
    f4 v1 = *(const f4*)gsrc1;

    for (int cc = 0; cc < 4; ++cc) {
        __syncthreads();   // previous round's reads (and weight staging) done
        *(f4*)ldst0 = v0;
        *(f4*)ldst1 = v1;
        __syncthreads();
        if (cc < 3) {      // prefetch next round, overlaps compute below
            gsrc0 += cstep; gsrc1 += cstep;
            v0 = *(const f4*)gsrc0;
            v1 = *(const f4*)gsrc1;
        }

        #pragma unroll
        for (int cl = 0; cl < 4; ++cl) {
            const int c = cc * 4 + cl;
            const f4 dv = *(const f4*)&dbase[cl * (TILE * LSTR) + doff];
            float dval[4] = {dv.x, dv.y, dv.z, dv.w};
            float tval[4];
            #pragma unroll
            for (int k = 0; k < 4; ++k)
                tval[k] = tbase[cl * (TILE * LSTR) + toff + k * LSTR];
            const float* wi = &wlds[0][c][og * 8];
            const float* wt = &wlds[1][c][og * 8];
            #pragma unroll
            for (int oo = 0; oo < 8; ++oo) {
                const float a = wi[oo], b = wt[oo];
                #pragma unroll
                for (int k = 0; k < 4; ++k) acc[k][oo] += a * dval[k] + b * tval[k];
            }
        }
    }

    // epilogue: float4 stores (4 consecutive y per thread)
    const int x  = (side == 0) ? (x0 + lx) : (y0 + lx);
    const int yb = (side == 0) ? (y0 + ly0) : (x0 + ly0);
    #pragma unroll
    for (int oo = 0; oo < 8; ++oo) {
        const int o = og * 8 + oo;
        const float av = Abuf[o * N + x] + Cbuf[o];
        const f4 bv = *(const f4*)&Bbuf[o * N + yb];
        f4 v;
        v.x = acc[0][oo] + av + bv.x;
        v.y = acc[1][oo] + av + bv.y;
        v.z = acc[2][oo] + av + bv.z;
        v.w = acc[3][oo] + av + bv.w;
        if (x - yb >= 0 && x - yb < 4) {
            const float dv = Dbuf[o * N + x];
            if (x == yb)     v.x += dv;
            if (x == yb + 1) v.y += dv;
            if (x == yb + 2) v.z += dv;
            if (x == yb + 3) v.w += dv;
        }
        __builtin_nontemporal_store(v, (f4*)&out[(size_t)o * N * N + (size_t)x * N + yb]);
    }
}

extern "C" void kernel_launch(void* const* d_in, const int* in_sizes, int n_in,
                              void* d_out, int out_size, void* d_ws, size_t ws_size,
                              hipStream_t stream) {
    (void)in_sizes; (void)n_in; (void)out_size; (void)ws_size;
    const float* X    = (const float*)d_in[0];
    const float* W    = (const float*)d_in[1];
    const float* bias = (const float*)d_in[2];
    float* out = (float*)d_out;
    float* ws  = (float*)d_ws;

    (void)hipMemsetAsync(ws + OFF_SUMS, 0, 32 * sizeof(float), stream);
    reduce_kernel<<<dim3(NSLAB, 16), 256, 0, stream>>>(X, ws);
    colreduce_kernel<<<dim3(8, 16), 256, 0, stream>>>(ws);
    fold_kernel<<<dim3(8, 16), 256, 0, stream>>>(W, bias, ws);
    main_kernel<<<NPAIRS, 1024, 0, stream>>>(X, W, ws, out);
}

// Round 5
// 3000.507 us; speedup vs baseline: 1.7445x; 1.0109x over previous
//
#include <hip/hip_runtime.h>
#include <hip/hip_bf16.h>

#define N 2048
#define TILE 32
#define LSTR 36                // LDS row stride (floats): 16B-aligned quads, bank-shift per row
#define NT 64                  // N / TILE
#define NPAIRS (NT*(NT+1)/2)   // 2080

typedef float f4 __attribute__((ext_vector_type(4)));

// ws float offsets
#define OFF_ROWSUM 0
#define OFF_COLSUM 32768
#define OFF_DIAG   65536
#define OFF_SUMS   98304      // [0..15]=diagsum, [16..31]=totsum
#define OFF_A      98336
#define OFF_B      131104
#define OFF_D      163872
#define OFF_C      196640
#define OFF_COLPART 196656    // 64 slabs * 16 c * 2048
#define NSLAB 64

// ---------------- reduce: rowsum, diag, colpart, diagsum/totsum ----------------
__global__ __launch_bounds__(256) void reduce_kernel(const float* __restrict__ X,
                                                     float* __restrict__ ws) {
    const int c = blockIdx.y;
    const int slab = blockIdx.x;          // 64 slabs of 32 rows
    const int tid = threadIdx.x;
    const int wave = tid >> 6, lane = tid & 63;

    float* rowsum = ws + OFF_ROWSUM;
    float* diagv  = ws + OFF_DIAG;
    float* sums   = ws + OFF_SUMS;
    float* colpart = ws + OFF_COLPART + (size_t)slab * 16 * N + (size_t)c * N;

    __shared__ float4 colbuf[4][512];

    float4 colacc[8];
    #pragma unroll
    for (int j = 0; j < 8; ++j) colacc[j] = make_float4(0.f, 0.f, 0.f, 0.f);
    float dacc = 0.f, totacc = 0.f;

    const int row0 = slab * 32 + wave * 8;
    const float* Xc = X + (size_t)c * N * N;
    for (int r = 0; r < 8; ++r) {
        const int row = row0 + r;
        const float4* rp = (const float4*)(Xc + (size_t)row * N);
        float part = 0.f;
        #pragma unroll
        for (int j = 0; j < 8; ++j) {
            const float4 v = rp[lane + 64 * j];
            part += (v.x + v.y) + (v.z + v.w);
            colacc[j].x += v.x; colacc[j].y += v.y;
            colacc[j].z += v.z; colacc[j].w += v.w;
            if (lane + 64 * j == (row >> 2)) {
                const int m = row & 3;
                const float dv = (m == 0) ? v.x : (m == 1) ? v.y : (m == 2) ? v.z : v.w;
                diagv[c * N + row] = dv;
                dacc += dv;
            }
        }
        #pragma unroll
        for (int s = 1; s < 64; s <<= 1) part += __shfl_xor(part, s);
        if (lane == 0) { rowsum[c * N + row] = part; totacc += part; }
    }
    #pragma unroll
    for (int s = 1; s < 64; s <<= 1) dacc += __shfl_xor(dacc, s);
    if (lane == 0) {
        atomicAdd(&sums[c], dacc);
        atomicAdd(&sums[16 + c], totacc);
    }

    // cross-wave column combine via LDS
    #pragma unroll
    for (int j = 0; j < 8; ++j) colbuf[wave][lane + 64 * j] = colacc[j];
    __syncthreads();
    #pragma unroll
    for (int j = 0; j < 2; ++j) {
        const int idx = tid + 256 * j;   // 0..511 float4 slots
        float4 s = colbuf[0][idx];
        const float4 s1 = colbuf[1][idx], s2 = colbuf[2][idx], s3 = colbuf[3][idx];
        s.x += s1.x + s2.x + s3.x; s.y += s1.y + s2.y + s3.y;
        s.z += s1.z + s2.z + s3.z; s.w += s1.w + s2.w + s3.w;
        ((float4*)colpart)[idx] = s;
    }
}

// ---------------- colreduce: colsum[c][y] = sum over slabs ----------------
__global__ __launch_bounds__(256) void colreduce_kernel(float* __restrict__ ws) {
    const int c = blockIdx.y;
    const int y = blockIdx.x * 256 + threadIdx.x;
    const float* colpart = ws + OFF_COLPART;
    float s = 0.f;
    for (int sl = 0; sl < NSLAB; ++sl)
        s += colpart[(size_t)sl * 16 * N + (size_t)c * N + y];
    ws[OFF_COLSUM + c * N + y] = s;
}

// ---------------- fold: A, B, D, C ----------------
__global__ __launch_bounds__(256) void fold_kernel(const float* __restrict__ W,
                                                   const float* __restrict__ bias,
                                                   float* __restrict__ ws) {
    const int o = blockIdx.y;
    const int x = blockIdx.x * 256 + threadIdx.x;
    const float invN = 1.f / (float)N;
    const float invN2 = invN * invN;
    const float* rowsum = ws + OFF_ROWSUM;
    const float* colsum = ws + OFF_COLSUM;
    const float* diagv  = ws + OFF_DIAG;
    const float* sums   = ws + OFF_SUMS;
    float* Abuf = ws + OFF_A;
    float* Bbuf = ws + OFF_B;
    float* Dbuf = ws + OFF_D;
    float* Cbuf = ws + OFF_C;

    if (blockIdx.x == 0 && threadIdx.x == 0) {
        float cacc = 0.f;
        #pragma unroll
        for (int c = 0; c < 16; ++c)
            cacc += (sums[c] * invN) * W[11 * 256 + c * 16 + o]
                  + (sums[16 + c] * invN2) * W[14 * 256 + c * 16 + o];
        float sb = 0.f;
        for (int p = 0; p < 15; ++p) sb += bias[p];
        Cbuf[o] = cacc + sb;
    }

    // uniform part of D (diagmean, totmean terms)
    float du = 0.f;
    #pragma unroll
    for (int c = 0; c < 16; ++c)
        du += (sums[c] * invN) * W[2 * 256 + c * 16 + o]
            + (sums[16 + c] * invN2) * W[4 * 256 + c * 16 + o];

    float a = 0.f, b = 0.f, d = 0.f;
    #pragma unroll
    for (int c = 0; c < 16; ++c) {
        const float dg = diagv[c * N + x];
        const float rm = rowsum[c * N + x] * invN;
        const float cm = colsum[c * N + x] * invN;
        a += dg * W[5 * 256 + c * 16 + o] + rm * W[12 * 256 + c * 16 + o] + cm * W[7 * 256 + c * 16 + o];
        b += dg * W[9 * 256 + c * 16 + o] + rm * W[13 * 256 + c * 16 + o] + cm * W[10 * 256 + c * 16 + o];
        d += dg * W[0 * 256 + c * 16 + o] + rm * W[3 * 256 + c * 16 + o]  + cm * W[1 * 256 + c * 16 + o];
    }
    Abuf[o * N + x] = a;
    Bbuf[o * N + x] = b;
    Dbuf[o * N + x] = d + du;
}

// ---------------- main: tile-pair kernel ----------------
// 1024 threads: og = tid>>9 (o-group of 8), side = (tid>>8)&1, t = tid&255.
// Each thread owns 4 consecutive-y pixels: lx = t>>3, ly = 4*(t&7)+k.
// Occupancy is forced to exactly 4 waves/EU (1 block/CU) so the allocator gets
// the full 128-VGPR budget. Bare launch_bounds / (1024,2) both produced a
// 64-VGPR cap -> acc spilled to scratch -> 9.8 GB of HBM scratch traffic.
__global__ __attribute__((amdgpu_flat_work_group_size(1024, 1024)))
__attribute__((amdgpu_waves_per_eu(4, 4)))
void main_kernel(const float* __restrict__ X,
                 const float* __restrict__ W,
                 const float* __restrict__ ws,
                 float* __restrict__ out) {
    // decode triangular pair (bx <= by)
    int rem = blockIdx.x, bx = 0;
    while (rem >= NT - bx) { rem -= NT - bx; ++bx; }
    const int by = bx + rem;
    const int x0 = bx * TILE, y0 = by * TILE;

    const int tid = threadIdx.x;
    const int og   = tid >> 9;          // o-group: outputs og*8 .. og*8+7
    const int side = (tid >> 8) & 1;    // pixel tile
    const int t    = tid & 255;

    __shared__ float lds[2][4][TILE][LSTR];
    __shared__ float wlds[2][16][16];   // [0]=identity (p8), [1]=transpose (p6)

    // stage weights once
    if (tid < 512) {
        const int p = tid >> 8;
        const int r = tid & 255;
        wlds[p][r >> 4][r & 15] = W[(p == 0 ? 8 : 6) * 256 + r];
    }

    const float* Abuf = ws + OFF_A;
    const float* Bbuf = ws + OFF_B;
    const float* Dbuf = ws + OFF_D;
    const float* Cbuf = ws + OFF_C;

    float acc[4][8];
    #pragma unroll
    for (int k = 0; k < 4; ++k)
        #pragma unroll
        for (int oo = 0; oo < 8; ++oo) acc[k][oo] = 0.f;

    // per-thread pixel geometry
    const int lx  = t >> 3;          // 0..31
    const int ly0 = 4 * (t & 7);     // 0,4,...,28
    const int doff = lx * LSTR + ly0;            // direct: 4 consecutive floats
    const int toff = ly0 * LSTR + lx;            // transpose: stride LSTR
    const float* dbase = &lds[side][0][0][0];
    const float* tbase = &lds[1 - side][0][0][0];

    // staging: tid = (ch<<8)|(row<<3)|qc
    const int scl  = (tid >> 8) & 3;
    const int srow = (tid >> 3) & 31;
    const int sqc  = tid & 7;
    const float* gsrc0 = X + (size_t)scl * N * N + (size_t)(x0 + srow) * N + (y0 + 4 * sqc);
    const float* gsrc1 = X + (size_t)scl * N * N + (size_t)(y0 + srow) * N + (x0 + 4 * sqc);
    float* ldst0 = &lds[0][scl][srow][4 * sqc];
    float* ldst1 = &lds[1][scl][srow][4 * sqc];
    const size_t cstep = (size_t)4 * N * N;

    f4 v0 = *(const f4*)gsrc0;
    f4 v1 = *(const f4*)gsrc1;

    for (int cc = 0; cc < 4; ++cc) {
        __syncthreads();   // previous round's reads (and weight staging) done
        *(f4*)ldst0 = v0;
        *(f4*)ldst1 = v1;
        __syncthreads();
        if (cc < 3) {      // prefetch next round, overlaps compute below
            gsrc0 += cstep; gsrc1 += cstep;
            v0 = *(const f4*)gsrc0;
            v1 = *(const f4*)gsrc1;
        }

        #pragma unroll
        for (int cl = 0; cl < 4; ++cl) {
            const int c = cc * 4 + cl;
            const f4 dv = *(const f4*)&dbase[cl * (TILE * LSTR) + doff];
            float dval[4] = {dv.x, dv.y, dv.z, dv.w};
            float tval[4];
            #pragma unroll
            for (int k = 0; k < 4; ++k)
                tval[k] = tbase[cl * (TILE * LSTR) + toff + k * LSTR];
            const float* wi = &wlds[0][c][og * 8];
            const float* wt = &wlds[1][c][og * 8];
            #pragma unroll
            for (int oo = 0; oo < 8; ++oo) {
                const float a = wi[oo], b = wt[oo];
                #pragma unroll
                for (int k = 0; k < 4; ++k) acc[k][oo] += a * dval[k] + b * tval[k];
            }
        }
    }

    // epilogue: float4 stores (4 consecutive y per thread)
    const int x  = (side == 0) ? (x0 + lx) : (y0 + lx);
    const int yb = (side == 0) ? (y0 + ly0) : (x0 + ly0);
    #pragma unroll
    for (int oo = 0; oo < 8; ++oo) {
        const int o = og * 8 + oo;
        const float av = Abuf[o * N + x] + Cbuf[o];
        const f4 bv = *(const f4*)&Bbuf[o * N + yb];
        f4 v;
        v.x = acc[0][oo] + av + bv.x;
        v.y = acc[1][oo] + av + bv.y;
        v.z = acc[2][oo] + av + bv.z;
        v.w = acc[3][oo] + av + bv.w;
        if (x - yb >= 0 && x - yb < 4) {
            const float dv = Dbuf[o * N + x];
            if (x == yb)     v.x += dv;
            if (x == yb + 1) v.y += dv;
            if (x == yb + 2) v.z += dv;
            if (x == yb + 3) v.w += dv;
        }
        __builtin_nontemporal_store(v, (f4*)&out[(size_t)o * N * N + (size_t)x * N + yb]);
    }
}

extern "C" void kernel_launch(void* const* d_in, const int* in_sizes, int n_in,
                              void* d_out, int out_size, void* d_ws, size_t ws_size,
                              hipStream_t stream) {
    (void)in_sizes; (void)n_in; (void)out_size; (void)ws_size;
    const float* X    = (const float*)d_in[0];
    const float* W    = (const float*)d_in[1];
    const float* bias = (const float*)d_in[2];
    float* out = (float*)d_out;
    float* ws  = (float*)d_ws;

    (void)hipMemsetAsync(ws + OFF_SUMS, 0, 32 * sizeof(float), stream);
    reduce_kernel<<<dim3(NSLAB, 16), 256, 0, stream>>>(X, ws);
    colreduce_kernel<<<dim3(8, 16), 256, 0, stream>>>(ws);
    fold_kernel<<<dim3(8, 16), 256, 0, stream>>>(W, bias, ws);
    main_kernel<<<NPAIRS, 1024, 0, stream>>>(X, W, ws, out);
}

// Round 6
// 1199.875 us; speedup vs baseline: 4.3624x; 2.5007x over previous
//
#include <hip/hip_runtime.h>
#include <hip/hip_bf16.h>

#define N 2048
#define T16 16
#define LSTR 20                // LDS row stride (floats): 16B-aligned quads + bank shift
#define NT2 128                // N / T16
#define NPAIR2 (NT2*(NT2+1)/2) // 8256

typedef float f4 __attribute__((ext_vector_type(4)));
typedef float f2 __attribute__((ext_vector_type(2)));

// ws float offsets
#define OFF_ROWSUM 0
#define OFF_COLSUM 32768
#define OFF_DIAG   65536
#define OFF_SUMS   98304      // [0..15]=diagsum, [16..31]=totsum
#define OFF_A      98336
#define OFF_B      131104
#define OFF_D      163872
#define OFF_C      196640
#define OFF_COLPART 196656    // 64 slabs * 16 c * 2048
#define NSLAB 64

// ---------------- reduce: rowsum, diag, colpart, diagsum/totsum ----------------
__global__ __launch_bounds__(256) void reduce_kernel(const float* __restrict__ X,
                                                     float* __restrict__ ws) {
    const int c = blockIdx.y;
    const int slab = blockIdx.x;          // 64 slabs of 32 rows
    const int tid = threadIdx.x;
    const int wave = tid >> 6, lane = tid & 63;

    float* rowsum = ws + OFF_ROWSUM;
    float* diagv  = ws + OFF_DIAG;
    float* sums   = ws + OFF_SUMS;
    float* colpart = ws + OFF_COLPART + (size_t)slab * 16 * N + (size_t)c * N;

    __shared__ float4 colbuf[4][512];

    float4 colacc[8];
    #pragma unroll
    for (int j = 0; j < 8; ++j) colacc[j] = make_float4(0.f, 0.f, 0.f, 0.f);
    float dacc = 0.f, totacc = 0.f;

    const int row0 = slab * 32 + wave * 8;
    const float* Xc = X + (size_t)c * N * N;
    for (int r = 0; r < 8; ++r) {
        const int row = row0 + r;
        const float4* rp = (const float4*)(Xc + (size_t)row * N);
        float part = 0.f;
        #pragma unroll
        for (int j = 0; j < 8; ++j) {
            const float4 v = rp[lane + 64 * j];
            part += (v.x + v.y) + (v.z + v.w);
            colacc[j].x += v.x; colacc[j].y += v.y;
            colacc[j].z += v.z; colacc[j].w += v.w;
            if (lane + 64 * j == (row >> 2)) {
                const int m = row & 3;
                const float dv = (m == 0) ? v.x : (m == 1) ? v.y : (m == 2) ? v.z : v.w;
                diagv[c * N + row] = dv;
                dacc += dv;
            }
        }
        #pragma unroll
        for (int s = 1; s < 64; s <<= 1) part += __shfl_xor(part, s);
        if (lane == 0) { rowsum[c * N + row] = part; totacc += part; }
    }
    #pragma unroll
    for (int s = 1; s < 64; s <<= 1) dacc += __shfl_xor(dacc, s);
    if (lane == 0) {
        atomicAdd(&sums[c], dacc);
        atomicAdd(&sums[16 + c], totacc);
    }

    // cross-wave column combine via LDS
    #pragma unroll
    for (int j = 0; j < 8; ++j) colbuf[wave][lane + 64 * j] = colacc[j];
    __syncthreads();
    #pragma unroll
    for (int j = 0; j < 2; ++j) {
        const int idx = tid + 256 * j;   // 0..511 float4 slots
        float4 s = colbuf[0][idx];
        const float4 s1 = colbuf[1][idx], s2 = colbuf[2][idx], s3 = colbuf[3][idx];
        s.x += s1.x + s2.x + s3.x; s.y += s1.y + s2.y + s3.y;
        s.z += s1.z + s2.z + s3.z; s.w += s1.w + s2.w + s3.w;
        ((float4*)colpart)[idx] = s;
    }
}

// ---------------- colreduce: colsum[c][y] = sum over slabs ----------------
__global__ __launch_bounds__(256) void colreduce_kernel(float* __restrict__ ws) {
    const int c = blockIdx.y;
    const int y = blockIdx.x * 256 + threadIdx.x;
    const float* colpart = ws + OFF_COLPART;
    float s = 0.f;
    for (int sl = 0; sl < NSLAB; ++sl)
        s += colpart[(size_t)sl * 16 * N + (size_t)c * N + y];
    ws[OFF_COLSUM + c * N + y] = s;
}

// ---------------- fold: A, B, D, C ----------------
__global__ __launch_bounds__(256) void fold_kernel(const float* __restrict__ W,
                                                   const float* __restrict__ bias,
                                                   float* __restrict__ ws) {
    const int o = blockIdx.y;
    const int x = blockIdx.x * 256 + threadIdx.x;
    const float invN = 1.f / (float)N;
    const float invN2 = invN * invN;
    const float* rowsum = ws + OFF_ROWSUM;
    const float* colsum = ws + OFF_COLSUM;
    const float* diagv  = ws + OFF_DIAG;
    const float* sums   = ws + OFF_SUMS;
    float* Abuf = ws + OFF_A;
    float* Bbuf = ws + OFF_B;
    float* Dbuf = ws + OFF_D;
    float* Cbuf = ws + OFF_C;

    if (blockIdx.x == 0 && threadIdx.x == 0) {
        float cacc = 0.f;
        #pragma unroll
        for (int c = 0; c < 16; ++c)
            cacc += (sums[c] * invN) * W[11 * 256 + c * 16 + o]
                  + (sums[16 + c] * invN2) * W[14 * 256 + c * 16 + o];
        float sb = 0.f;
        for (int p = 0; p < 15; ++p) sb += bias[p];
        Cbuf[o] = cacc + sb;
    }

    // uniform part of D (diagmean, totmean terms)
    float du = 0.f;
    #pragma unroll
    for (int c = 0; c < 16; ++c)
        du += (sums[c] * invN) * W[2 * 256 + c * 16 + o]
            + (sums[16 + c] * invN2) * W[4 * 256 + c * 16 + o];

    float a = 0.f, b = 0.f, d = 0.f;
    #pragma unroll
    for (int c = 0; c < 16; ++c) {
        const float dg = diagv[c * N + x];
        const float rm = rowsum[c * N + x] * invN;
        const float cm = colsum[c * N + x] * invN;
        a += dg * W[5 * 256 + c * 16 + o] + rm * W[12 * 256 + c * 16 + o] + cm * W[7 * 256 + c * 16 + o];
        b += dg * W[9 * 256 + c * 16 + o] + rm * W[13 * 256 + c * 16 + o] + cm * W[10 * 256 + c * 16 + o];
        d += dg * W[0 * 256 + c * 16 + o] + rm * W[3 * 256 + c * 16 + o]  + cm * W[1 * 256 + c * 16 + o];
    }
    Abuf[o * N + x] = a;
    Bbuf[o * N + x] = b;
    Dbuf[o * N + x] = d + du;
}

// ---------------- main: 16x16 tile-pair kernel, 512 threads ----------------
// og = tid>>8 (8 outputs each), side = (tid>>7)&1, t = tid&127.
// Each thread owns 2 consecutive-y pixels: lx = t>>3, ly = 2*(t&7)+{0,1}.
// Per-thread acc = 8 float2 = 16 VGPRs -> total demand ~50 VGPRs, safely under
// the 64-VGPR ceiling the allocator insists on (1024-thread shapes spilled).
__global__ __launch_bounds__(512) void main_kernel(const float* __restrict__ X,
                                                   const float* __restrict__ W,
                                                   const float* __restrict__ ws,
                                                   float* __restrict__ out) {
    // decode triangular pair (bx <= by)
    int rem = blockIdx.x, bx = 0;
    while (rem >= NT2 - bx) { rem -= NT2 - bx; ++bx; }
    const int by = bx + rem;
    const int x0 = bx * T16, y0 = by * T16;

    const int tid = threadIdx.x;
    const int og   = tid >> 8;          // o-group: outputs og*8 .. og*8+7
    const int side = (tid >> 7) & 1;    // pixel tile
    const int t    = tid & 127;

    __shared__ float lds[2][4][T16][LSTR];
    __shared__ float wlds[2][256];      // [0]=identity (p8), [1]=transpose (p6)

    // stage weights once (all 512 threads)
    {
        const int p = tid >> 8;
        const int r = tid & 255;
        wlds[p][r] = W[(p == 0 ? 8 : 6) * 256 + r];
    }

    const float* Abuf = ws + OFF_A;
    const float* Bbuf = ws + OFF_B;
    const float* Dbuf = ws + OFF_D;
    const float* Cbuf = ws + OFF_C;

    f2 acc[8];
    #pragma unroll
    for (int oo = 0; oo < 8; ++oo) acc[oo] = (f2)(0.f);

    // per-thread pixel geometry
    const int lx  = t >> 3;          // 0..15
    const int ly0 = 2 * (t & 7);     // 0..14 even
    const int doff  = lx * LSTR + ly0;       // direct: 2 consecutive floats
    const int toff0 = ly0 * LSTR + lx;       // transpose: +LSTR for second pixel
    const int CHS = T16 * LSTR;
    const float* dbase = &lds[side][0][0][0];
    const float* tbase = &lds[1 - side][0][0][0];

    // staging: tid = (stile<<8)|(sch<<6)|(srow<<2)|sq  -> one f4 per thread per cc
    const int stile = tid >> 8;
    const int sch   = (tid >> 6) & 3;
    const int srow  = (tid >> 2) & 15;
    const int sq    = tid & 3;
    const int r0 = (stile == 0) ? x0 : y0;
    const int c0 = (stile == 0) ? y0 : x0;
    const float* gsrc = X + (size_t)sch * N * N + (size_t)(r0 + srow) * N + (c0 + 4 * sq);
    float* ldst = &lds[stile][sch][srow][4 * sq];
    const size_t cstep = (size_t)4 * N * N;

    f4 v = *(const f4*)gsrc;

    for (int cc = 0; cc < 4; ++cc) {
        __syncthreads();   // previous round's reads (and weight staging) done
        *(f4*)ldst = v;
        __syncthreads();
        if (cc < 3) {      // prefetch next round, overlaps compute below
            gsrc += cstep;
            v = *(const f4*)gsrc;
        }

        #pragma unroll
        for (int cl = 0; cl < 4; ++cl) {
            const int c = cc * 4 + cl;
            const f2 d2 = *(const f2*)&dbase[cl * CHS + doff];
            f2 t2;
            t2.x = tbase[cl * CHS + toff0];
            t2.y = tbase[cl * CHS + toff0 + LSTR];
            const f4 wi0 = *(const f4*)&wlds[0][c * 16 + og * 8];
            const f4 wi1 = *(const f4*)&wlds[0][c * 16 + og * 8 + 4];
            const f4 wt0 = *(const f4*)&wlds[1][c * 16 + og * 8];
            const f4 wt1 = *(const f4*)&wlds[1][c * 16 + og * 8 + 4];
            #pragma unroll
            for (int oo = 0; oo < 4; ++oo) {
                acc[oo]     += wi0[oo] * d2 + wt0[oo] * t2;
                acc[oo + 4] += wi1[oo] * d2 + wt1[oo] * t2;
            }
        }
    }

    // epilogue: float2 stores (2 consecutive y per thread)
    const int x  = (side == 0) ? (x0 + lx) : (y0 + lx);
    const int yb = (side == 0) ? (y0 + ly0) : (x0 + ly0);
    #pragma unroll
    for (int oo = 0; oo < 8; ++oo) {
        const int o = og * 8 + oo;
        const float av = Abuf[o * N + x] + Cbuf[o];
        const f2 bv = *(const f2*)&Bbuf[o * N + yb];
        f2 v2 = acc[oo];
        v2.x += av + bv.x;
        v2.y += av + bv.y;
        const int dxy = x - yb;
        if (dxy == 0 || dxy == 1) {
            const float dv = Dbuf[o * N + x];
            if (dxy == 0) v2.x += dv; else v2.y += dv;
        }
        __builtin_nontemporal_store(v2, (f2*)&out[(size_t)o * N * N + (size_t)x * N + yb]);
    }
}

extern "C" void kernel_launch(void* const* d_in, const int* in_sizes, int n_in,
                              void* d_out, int out_size, void* d_ws, size_t ws_size,
                              hipStream_t stream) {
    (void)in_sizes; (void)n_in; (void)out_size; (void)ws_size;
    const float* X    = (const float*)d_in[0];
    const float* W    = (const float*)d_in[1];
    const float* bias = (const float*)d_in[2];
    float* out = (float*)d_out;
    float* ws  = (float*)d_ws;

    (void)hipMemsetAsync(ws + OFF_SUMS, 0, 32 * sizeof(float), stream);
    reduce_kernel<<<dim3(NSLAB, 16), 256, 0, stream>>>(X, ws);
    colreduce_kernel<<<dim3(8, 16), 256, 0, stream>>>(ws);
    fold_kernel<<<dim3(8, 16), 256, 0, stream>>>(W, bias, ws);
    main_kernel<<<NPAIR2, 512, 0, stream>>>(X, W, ws, out);
}

// Round 7
// 409.067 us; speedup vs baseline: 12.7957x; 2.9332x over previous
//
#include <hip/hip_runtime.h>
#include <hip/hip_bf16.h>

#define N 2048
#define T16 16
#define LSTR 20                // LDS row stride (floats): 16B-aligned quads + bank shift
#define NT2 128                // N / T16
#define NPAIR2 (NT2*(NT2+1)/2) // 8256

typedef float f4 __attribute__((ext_vector_type(4)));
typedef float f2 __attribute__((ext_vector_type(2)));

// ws float offsets
#define OFF_ROWSUM 0
#define OFF_COLSUM 32768
#define OFF_DIAG   65536
#define OFF_SUMS   98304      // [0..15]=diagsum, [16..31]=totsum
#define OFF_A      98336
#define OFF_B      131104
#define OFF_D      163872
#define OFF_C      196640
#define OFF_COLPART 196656    // 64 slabs * 16 c * 2048
#define NSLAB 64

// ---------------- reduce: rowsum, diag, colpart, diagsum/totsum ----------------
__global__ __launch_bounds__(256) void reduce_kernel(const float* __restrict__ X,
                                                     float* __restrict__ ws) {
    const int c = blockIdx.y;
    const int slab = blockIdx.x;          // 64 slabs of 32 rows
    const int tid = threadIdx.x;
    const int wave = tid >> 6, lane = tid & 63;

    float* rowsum = ws + OFF_ROWSUM;
    float* diagv  = ws + OFF_DIAG;
    float* sums   = ws + OFF_SUMS;
    float* colpart = ws + OFF_COLPART + (size_t)slab * 16 * N + (size_t)c * N;

    __shared__ float4 colbuf[4][512];

    float4 colacc[8];
    #pragma unroll
    for (int j = 0; j < 8; ++j) colacc[j] = make_float4(0.f, 0.f, 0.f, 0.f);
    float dacc = 0.f, totacc = 0.f;

    const int row0 = slab * 32 + wave * 8;
    const float* Xc = X + (size_t)c * N * N;
    for (int r = 0; r < 8; ++r) {
        const int row = row0 + r;
        const float4* rp = (const float4*)(Xc + (size_t)row * N);
        float part = 0.f;
        #pragma unroll
        for (int j = 0; j < 8; ++j) {
            const float4 v = rp[lane + 64 * j];
            part += (v.x + v.y) + (v.z + v.w);
            colacc[j].x += v.x; colacc[j].y += v.y;
            colacc[j].z += v.z; colacc[j].w += v.w;
            if (lane + 64 * j == (row >> 2)) {
                const int m = row & 3;
                const float dv = (m == 0) ? v.x : (m == 1) ? v.y : (m == 2) ? v.z : v.w;
                diagv[c * N + row] = dv;
                dacc += dv;
            }
        }
        #pragma unroll
        for (int s = 1; s < 64; s <<= 1) part += __shfl_xor(part, s);
        if (lane == 0) { rowsum[c * N + row] = part; totacc += part; }
    }
    #pragma unroll
    for (int s = 1; s < 64; s <<= 1) dacc += __shfl_xor(dacc, s);
    if (lane == 0) {
        atomicAdd(&sums[c], dacc);
        atomicAdd(&sums[16 + c], totacc);
    }

    // cross-wave column combine via LDS
    #pragma unroll
    for (int j = 0; j < 8; ++j) colbuf[wave][lane + 64 * j] = colacc[j];
    __syncthreads();
    #pragma unroll
    for (int j = 0; j < 2; ++j) {
        const int idx = tid + 256 * j;   // 0..511 float4 slots
        float4 s = colbuf[0][idx];
        const float4 s1 = colbuf[1][idx], s2 = colbuf[2][idx], s3 = colbuf[3][idx];
        s.x += s1.x + s2.x + s3.x; s.y += s1.y + s2.y + s3.y;
        s.z += s1.z + s2.z + s3.z; s.w += s1.w + s2.w + s3.w;
        ((float4*)colpart)[idx] = s;
    }
}

// ---------------- colreduce: colsum[c][y] = sum over slabs ----------------
__global__ __launch_bounds__(256) void colreduce_kernel(float* __restrict__ ws) {
    const int c = blockIdx.y;
    const int y = blockIdx.x * 256 + threadIdx.x;
    const float* colpart = ws + OFF_COLPART;
    float s = 0.f;
    for (int sl = 0; sl < NSLAB; ++sl)
        s += colpart[(size_t)sl * 16 * N + (size_t)c * N + y];
    ws[OFF_COLSUM + c * N + y] = s;
}

// ---------------- fold: A, B, D, C ----------------
__global__ __launch_bounds__(256) void fold_kernel(const float* __restrict__ W,
                                                   const float* __restrict__ bias,
                                                   float* __restrict__ ws) {
    const int o = blockIdx.y;
    const int x = blockIdx.x * 256 + threadIdx.x;
    const float invN = 1.f / (float)N;
    const float invN2 = invN * invN;
    const float* rowsum = ws + OFF_ROWSUM;
    const float* colsum = ws + OFF_COLSUM;
    const float* diagv  = ws + OFF_DIAG;
    const float* sums   = ws + OFF_SUMS;
    float* Abuf = ws + OFF_A;
    float* Bbuf = ws + OFF_B;
    float* Dbuf = ws + OFF_D;
    float* Cbuf = ws + OFF_C;

    if (blockIdx.x == 0 && threadIdx.x == 0) {
        float cacc = 0.f;
        #pragma unroll
        for (int c = 0; c < 16; ++c)
            cacc += (sums[c] * invN) * W[11 * 256 + c * 16 + o]
                  + (sums[16 + c] * invN2) * W[14 * 256 + c * 16 + o];
        float sb = 0.f;
        for (int p = 0; p < 15; ++p) sb += bias[p];
        Cbuf[o] = cacc + sb;
    }

    // uniform part of D (diagmean, totmean terms)
    float du = 0.f;
    #pragma unroll
    for (int c = 0; c < 16; ++c)
        du += (sums[c] * invN) * W[2 * 256 + c * 16 + o]
            + (sums[16 + c] * invN2) * W[4 * 256 + c * 16 + o];

    float a = 0.f, b = 0.f, d = 0.f;
    #pragma unroll
    for (int c = 0; c < 16; ++c) {
        const float dg = diagv[c * N + x];
        const float rm = rowsum[c * N + x] * invN;
        const float cm = colsum[c * N + x] * invN;
        a += dg * W[5 * 256 + c * 16 + o] + rm * W[12 * 256 + c * 16 + o] + cm * W[7 * 256 + c * 16 + o];
        b += dg * W[9 * 256 + c * 16 + o] + rm * W[13 * 256 + c * 16 + o] + cm * W[10 * 256 + c * 16 + o];
        d += dg * W[0 * 256 + c * 16 + o] + rm * W[3 * 256 + c * 16 + o]  + cm * W[1 * 256 + c * 16 + o];
    }
    Abuf[o * N + x] = a;
    Bbuf[o * N + x] = b;
    Dbuf[o * N + x] = d + du;
}

// ---------------- main: 16x16 tile-pair kernel, 512 threads ----------------
// og = tid>>8 (8 outputs each, wave-uniform -> readfirstlane), side = (tid>>7)&1,
// t = tid&127; each thread owns 2 consecutive-y pixels.
// Weights are read straight from W at wave-uniform addresses (forced via
// readfirstlane) -> s_load into SGPRs: zero VGPR pressure from weights.
// Round 6 kept 16 f4 weights in VGPRs -> spill -> 3.7 GB scratch traffic.
__global__ __launch_bounds__(512) void main_kernel(const float* __restrict__ X,
                                                   const float* __restrict__ W,
                                                   const float* __restrict__ ws,
                                                   float* __restrict__ out) {
    // decode triangular pair (bx <= by)
    int rem = blockIdx.x, bx = 0;
    while (rem >= NT2 - bx) { rem -= NT2 - bx; ++bx; }
    const int by = bx + rem;
    const int x0 = bx * T16, y0 = by * T16;

    const int tid = threadIdx.x;
    const int og   = __builtin_amdgcn_readfirstlane(tid >> 8);  // uniform o-group
    const int side = (tid >> 7) & 1;    // pixel tile
    const int t    = tid & 127;

    __shared__ float lds[2][4][T16][LSTR];

    const float* Abuf = ws + OFF_A;
    const float* Bbuf = ws + OFF_B;
    const float* Dbuf = ws + OFF_D;
    const float* Cbuf = ws + OFF_C;

    // uniform weight bases (o = og*8 .. og*8+7)
    const float* Wid = W + 8 * 256 + og * 8;   // identity partition
    const float* Wtr = W + 6 * 256 + og * 8;   // transpose partition

    f2 acc[8];
    #pragma unroll
    for (int oo = 0; oo < 8; ++oo) acc[oo] = (f2)(0.f);

    // per-thread pixel geometry
    const int lx  = t >> 3;          // 0..15
    const int ly0 = 2 * (t & 7);     // 0..14 even
    const int doff  = lx * LSTR + ly0;       // direct: 2 consecutive floats
    const int toff0 = ly0 * LSTR + lx;       // transpose: +LSTR for second pixel
    const int CHS = T16 * LSTR;
    const float* dbase = &lds[side][0][0][0];
    const float* tbase = &lds[1 - side][0][0][0];

    // staging: tid = (stile<<8)|(sch<<6)|(srow<<2)|sq  -> one f4 per thread per cc
    const int stile = tid >> 8;
    const int sch   = (tid >> 6) & 3;
    const int srow  = (tid >> 2) & 15;
    const int sq    = tid & 3;
    const int r0 = (stile == 0) ? x0 : y0;
    const int c0 = (stile == 0) ? y0 : x0;
    const float* gsrc = X + (size_t)sch * N * N + (size_t)(r0 + srow) * N + (c0 + 4 * sq);
    float* ldst = &lds[stile][sch][srow][4 * sq];
    const size_t cstep = (size_t)4 * N * N;

    f4 v = *(const f4*)gsrc;

    for (int cc = 0; cc < 4; ++cc) {
        __syncthreads();   // previous round's reads done
        *(f4*)ldst = v;
        __syncthreads();
        if (cc < 3) {      // prefetch next round, overlaps compute below
            gsrc += cstep;
            v = *(const f4*)gsrc;
        }

        #pragma unroll
        for (int cl = 0; cl < 4; ++cl) {
            const int c = cc * 4 + cl;
            const f2 d2 = *(const f2*)&dbase[cl * CHS + doff];
            f2 t2;
            t2.x = tbase[cl * CHS + toff0];
            t2.y = tbase[cl * CHS + toff0 + LSTR];
            // uniform addresses -> s_load_dwordx4 (SGPR), no VGPR pressure
            const f4 wi0 = *(const f4*)&Wid[c * 16];
            const f4 wi1 = *(const f4*)&Wid[c * 16 + 4];
            const f4 wt0 = *(const f4*)&Wtr[c * 16];
            const f4 wt1 = *(const f4*)&Wtr[c * 16 + 4];
            #pragma unroll
            for (int oo = 0; oo < 4; ++oo) {
                acc[oo]     += wi0[oo] * d2 + wt0[oo] * t2;
                acc[oo + 4] += wi1[oo] * d2 + wt1[oo] * t2;
            }
        }
    }

    // epilogue: float2 stores (2 consecutive y per thread)
    const int x  = (side == 0) ? (x0 + lx) : (y0 + lx);
    const int yb = (side == 0) ? (y0 + ly0) : (x0 + ly0);
    #pragma unroll
    for (int oo = 0; oo < 8; ++oo) {
        const int o = og * 8 + oo;
        const float av = Abuf[o * N + x] + Cbuf[o];
        const f2 bv = *(const f2*)&Bbuf[o * N + yb];
        f2 v2 = acc[oo];
        v2.x += av + bv.x;
        v2.y += av + bv.y;
        const int dxy = x - yb;
        if (dxy == 0 || dxy == 1) {
            const float dv = Dbuf[o * N + x];
            if (dxy == 0) v2.x += dv; else v2.y += dv;
        }
        __builtin_nontemporal_store(v2, (f2*)&out[(size_t)o * N * N + (size_t)x * N + yb]);
    }
}

extern "C" void kernel_launch(void* const* d_in, const int* in_sizes, int n_in,
                              void* d_out, int out_size, void* d_ws, size_t ws_size,
                              hipStream_t stream) {
    (void)in_sizes; (void)n_in; (void)out_size; (void)ws_size;
    const float* X    = (const float*)d_in[0];
    const float* W    = (const float*)d_in[1];
    const float* bias = (const float*)d_in[2];
    float* out = (float*)d_out;
    float* ws  = (float*)d_ws;

    (void)hipMemsetAsync(ws + OFF_SUMS, 0, 32 * sizeof(float), stream);
    reduce_kernel<<<dim3(NSLAB, 16), 256, 0, stream>>>(X, ws);
    colreduce_kernel<<<dim3(8, 16), 256, 0, stream>>>(ws);
    fold_kernel<<<dim3(8, 16), 256, 0, stream>>>(W, bias, ws);
    main_kernel<<<NPAIR2, 512, 0, stream>>>(X, W, ws, out);
}

// Round 8
// 325.427 us; speedup vs baseline: 16.0844x; 1.2570x over previous
//
#include <hip/hip_runtime.h>
#include <hip/hip_bf16.h>

#define N 2048

typedef float f4 __attribute__((ext_vector_type(4)));
typedef float f2 __attribute__((ext_vector_type(2)));
typedef unsigned int u32;
typedef u32 u32x4 __attribute__((ext_vector_type(4)));

// ws float offsets
#define OFF_ROWSUM 0
#define OFF_COLSUM 32768
#define OFF_DIAG   65536
#define OFF_SUMS   98304      // [0..15]=diagsum, [16..31]=totsum
#define OFF_A      98336
#define OFF_B      131104
#define OFF_D      163872
#define OFF_C      196640
#define OFF_COLPART 196656    // 64 slabs * 16 c * 2048
#define NSLAB 64

// ---------------- reduce: rowsum, diag, colpart, diagsum/totsum ----------------
__global__ __launch_bounds__(256) void reduce_kernel(const float* __restrict__ X,
                                                     float* __restrict__ ws) {
    const int c = blockIdx.y;
    const int slab = blockIdx.x;          // 64 slabs of 32 rows
    const int tid = threadIdx.x;
    const int wave = tid >> 6, lane = tid & 63;

    float* rowsum = ws + OFF_ROWSUM;
    float* diagv  = ws + OFF_DIAG;
    float* sums   = ws + OFF_SUMS;
    float* colpart = ws + OFF_COLPART + (size_t)slab * 16 * N + (size_t)c * N;

    __shared__ float4 colbuf[4][512];

    float4 colacc[8];
    #pragma unroll
    for (int j = 0; j < 8; ++j) colacc[j] = make_float4(0.f, 0.f, 0.f, 0.f);
    float dacc = 0.f, totacc = 0.f;

    const int row0 = slab * 32 + wave * 8;
    const float* Xc = X + (size_t)c * N * N;
    for (int r = 0; r < 8; ++r) {
        const int row = row0 + r;
        const float4* rp = (const float4*)(Xc + (size_t)row * N);
        float part = 0.f;
        #pragma unroll
        for (int j = 0; j < 8; ++j) {
            const float4 v = rp[lane + 64 * j];
            part += (v.x + v.y) + (v.z + v.w);
            colacc[j].x += v.x; colacc[j].y += v.y;
            colacc[j].z += v.z; colacc[j].w += v.w;
            if (lane + 64 * j == (row >> 2)) {
                const int m = row & 3;
                const float dv = (m == 0) ? v.x : (m == 1) ? v.y : (m == 2) ? v.z : v.w;
                diagv[c * N + row] = dv;
                dacc += dv;
            }
        }
        #pragma unroll
        for (int s = 1; s < 64; s <<= 1) part += __shfl_xor(part, s);
        if (lane == 0) { rowsum[c * N + row] = part; totacc += part; }
    }
    #pragma unroll
    for (int s = 1; s < 64; s <<= 1) dacc += __shfl_xor(dacc, s);
    if (lane == 0) {
        atomicAdd(&sums[c], dacc);
        atomicAdd(&sums[16 + c], totacc);
    }

    // cross-wave column combine via LDS
    #pragma unroll
    for (int j = 0; j < 8; ++j) colbuf[wave][lane + 64 * j] = colacc[j];
    __syncthreads();
    #pragma unroll
    for (int j = 0; j < 2; ++j) {
        const int idx = tid + 256 * j;   // 0..511 float4 slots
        float4 s = colbuf[0][idx];
        const float4 s1 = colbuf[1][idx], s2 = colbuf[2][idx], s3 = colbuf[3][idx];
        s.x += s1.x + s2.x + s3.x; s.y += s1.y + s2.y + s3.y;
        s.z += s1.z + s2.z + s3.z; s.w += s1.w + s2.w + s3.w;
        ((float4*)colpart)[idx] = s;
    }
}

// ---------------- colreduce: colsum[c][y] = sum over slabs ----------------
__global__ __launch_bounds__(256) void colreduce_kernel(float* __restrict__ ws) {
    const int c = blockIdx.y;
    const int y = blockIdx.x * 256 + threadIdx.x;
    const float* colpart = ws + OFF_COLPART;
    float s = 0.f;
    for (int sl = 0; sl < NSLAB; ++sl)
        s += colpart[(size_t)sl * 16 * N + (size_t)c * N + y];
    ws[OFF_COLSUM + c * N + y] = s;
}

// ---------------- fold: A, B, D, C ----------------
__global__ __launch_bounds__(256) void fold_kernel(const float* __restrict__ W,
                                                   const float* __restrict__ bias,
                                                   float* __restrict__ ws) {
    const int o = blockIdx.y;
    const int x = blockIdx.x * 256 + threadIdx.x;
    const float invN = 1.f / (float)N;
    const float invN2 = invN * invN;
    const float* rowsum = ws + OFF_ROWSUM;
    const float* colsum = ws + OFF_COLSUM;
    const float* diagv  = ws + OFF_DIAG;
    const float* sums   = ws + OFF_SUMS;
    float* Abuf = ws + OFF_A;
    float* Bbuf = ws + OFF_B;
    float* Dbuf = ws + OFF_D;
    float* Cbuf = ws + OFF_C;

    if (blockIdx.x == 0 && threadIdx.x == 0) {
        float cacc = 0.f;
        #pragma unroll
        for (int c = 0; c < 16; ++c)
            cacc += (sums[c] * invN) * W[11 * 256 + c * 16 + o]
                  + (sums[16 + c] * invN2) * W[14 * 256 + c * 16 + o];
        float sb = 0.f;
        for (int p = 0; p < 15; ++p) sb += bias[p];
        Cbuf[o] = cacc + sb;
    }

    // uniform part of D (diagmean, totmean terms)
    float du = 0.f;
    #pragma unroll
    for (int c = 0; c < 16; ++c)
        du += (sums[c] * invN) * W[2 * 256 + c * 16 + o]
            + (sums[16 + c] * invN2) * W[4 * 256 + c * 16 + o];

    float a = 0.f, b = 0.f, d = 0.f;
    #pragma unroll
    for (int c = 0; c < 16; ++c) {
        const float dg = diagv[c * N + x];
        const float rm = rowsum[c * N + x] * invN;
        const float cm = colsum[c * N + x] * invN;
        a += dg * W[5 * 256 + c * 16 + o] + rm * W[12 * 256 + c * 16 + o] + cm * W[7 * 256 + c * 16 + o];
        b += dg * W[9 * 256 + c * 16 + o] + rm * W[13 * 256 + c * 16 + o] + cm * W[10 * 256 + c * 16 + o];
        d += dg * W[0 * 256 + c * 16 + o] + rm * W[3 * 256 + c * 16 + o]  + cm * W[1 * 256 + c * 16 + o];
    }
    Abuf[o * N + x] = a;
    Bbuf[o * N + x] = b;
    Dbuf[o * N + x] = d + du;
}

// ---------------- pack: XT32[c2][t][s] = bf16pair(X[2c2][s][t], X[2c2+1][s][t]) ----------------
// Tile: 32 source rows (s) x 128 source cols (t), one channel-pair per block.
// Reads: 512B-contiguous f4 rows; writes: 8x128B contiguous chunks per inst.
__global__ __launch_bounds__(256, 4) void pack_kernel(const float* __restrict__ X,
                                                      u32* __restrict__ XT) {
    const int s0 = blockIdx.x * 32;    // 64 panels
    const int t0 = blockIdx.y * 128;   // 16 panels
    const int cz = blockIdx.z;         // 8 channel pairs
    const int tid = threadIdx.x;

    __shared__ float lds[2][32][132];

    #pragma unroll
    for (int j = 0; j < 8; ++j) {
        const int idx = tid + 256 * j;           // 0..2047 f4 slots
        const int ch = idx >> 10, row = (idx >> 5) & 31, c4 = idx & 31;
        const f4 v = *(const f4*)(X + (size_t)(2 * cz + ch) * N * N + (size_t)(s0 + row) * N + t0 + 4 * c4);
        *(f4*)&lds[ch][row][4 * c4] = v;
    }
    __syncthreads();
    #pragma unroll
    for (int j = 0; j < 4; ++j) {
        const int idx = tid + 256 * j;           // 0..1023 u32x4 chunks
        const int tt = idx >> 3, xq = idx & 7;
        u32x4 w;
        #pragma unroll
        for (int i = 0; i < 4; ++i) {
            const int sl = 4 * xq + i;
            const unsigned short lo = __builtin_bit_cast(unsigned short, __float2bfloat16(lds[0][sl][tt]));
            const unsigned short hi = __builtin_bit_cast(unsigned short, __float2bfloat16(lds[1][sl][tt]));
            w[i] = (u32)lo | ((u32)hi << 16);
        }
        __builtin_nontemporal_store(w, (u32x4*)(XT + (size_t)cz * N * N + (size_t)(t0 + tt) * N + s0 + 4 * xq));
    }
}

// ---------------- main: fully-streaming kernel ----------------
// 256 threads: og = tid>>7 (8 outputs), qi = tid&127 -> f4 pixel-quad.
// No LDS, no tiles. X read 1KB/inst, XT (bf16 pairs) 512B/inst, out 1KB/inst.
// XT lives in out's upper half: slot (c2,x,y) == out slot (8+c2,x,y), so each
// block only reads its OWN pixels' XT; __syncthreads before stores orders
// read-before-overwrite within the block.
__global__ __launch_bounds__(256, 4) void main_kernel(const float* __restrict__ X,
                                                      const float* __restrict__ W,
                                                      const float* __restrict__ ws,
                                                      const u32* __restrict__ XT,
                                                      float* __restrict__ out) {
    const int tid = threadIdx.x;
    const int og = __builtin_amdgcn_readfirstlane(tid >> 7);
    const int qi = tid & 127;
    const size_t p = ((size_t)blockIdx.x * 128 + qi) * 4;   // pixel flat index
    const int x = (int)(p >> 11);
    const int y = (int)(p & 2047);

    const float* Wid = W + 8 * 256 + og * 8;   // identity partition, o-slice
    const float* Wtr = W + 6 * 256 + og * 8;   // transpose partition, o-slice

    f4 acc[8];
    #pragma unroll
    for (int oo = 0; oo < 8; ++oo) acc[oo] = (f4)(0.f);

    #pragma unroll 2
    for (int c2 = 0; c2 < 8; ++c2) {
        const int c0 = 2 * c2;
        const f4 xa = *(const f4*)(X + (size_t)c0 * N * N + p);
        const f4 xb = *(const f4*)(X + (size_t)(c0 + 1) * N * N + p);
        const u32x4 xt = *(const u32x4*)(XT + (size_t)c2 * N * N + p);
        f4 ta, tb;
        #pragma unroll
        for (int i = 0; i < 4; ++i) {
            ta[i] = __builtin_bit_cast(float, xt[i] << 16);
            tb[i] = __builtin_bit_cast(float, xt[i] & 0xffff0000u);
        }
        const f4 wiA0 = *(const f4*)&Wid[c0 * 16];
        const f4 wiA1 = *(const f4*)&Wid[c0 * 16 + 4];
        const f4 wiB0 = *(const f4*)&Wid[c0 * 16 + 16];
        const f4 wiB1 = *(const f4*)&Wid[c0 * 16 + 20];
        const f4 wtA0 = *(const f4*)&Wtr[c0 * 16];
        const f4 wtA1 = *(const f4*)&Wtr[c0 * 16 + 4];
        const f4 wtB0 = *(const f4*)&Wtr[c0 * 16 + 16];
        const f4 wtB1 = *(const f4*)&Wtr[c0 * 16 + 20];
        #pragma unroll
        for (int oo = 0; oo < 4; ++oo) {
            acc[oo]     += wiA0[oo] * xa + wiB0[oo] * xb + wtA0[oo] * ta + wtB0[oo] * tb;
            acc[oo + 4] += wiA1[oo] * xa + wiB1[oo] * xb + wtA1[oo] * ta + wtB1[oo] * tb;
        }
    }

    __syncthreads();   // all XT reads in this block complete before upper-half stores

    const float* Abuf = ws + OFF_A;
    const float* Bbuf = ws + OFF_B;
    const float* Dbuf = ws + OFF_D;
    const float* Cbuf = ws + OFF_C;

    #pragma unroll
    for (int oo = 0; oo < 8; ++oo) {
        const int o = og * 8 + oo;
        const float av = Abuf[o * N + x] + Cbuf[o];
        const f4 bv = *(const f4*)&Bbuf[o * N + y];
        f4 v = acc[oo] + av + bv;
        const int d = x - y;
        if (d >= 0 && d < 4) v[d] += Dbuf[o * N + x];
        __builtin_nontemporal_store(v, (f4*)(out + (size_t)o * N * N + p));
    }
}

extern "C" void kernel_launch(void* const* d_in, const int* in_sizes, int n_in,
                              void* d_out, int out_size, void* d_ws, size_t ws_size,
                              hipStream_t stream) {
    (void)in_sizes; (void)n_in; (void)out_size; (void)ws_size;
    const float* X    = (const float*)d_in[0];
    const float* W    = (const float*)d_in[1];
    const float* bias = (const float*)d_in[2];
    float* out = (float*)d_out;
    float* ws  = (float*)d_ws;
    u32* XT = (u32*)(out + (size_t)8 * N * N);   // upper half of d_out as scratch

    (void)hipMemsetAsync(ws + OFF_SUMS, 0, 32 * sizeof(float), stream);
    reduce_kernel<<<dim3(NSLAB, 16), 256, 0, stream>>>(X, ws);
    colreduce_kernel<<<dim3(8, 16), 256, 0, stream>>>(ws);
    fold_kernel<<<dim3(8, 16), 256, 0, stream>>>(W, bias, ws);
    pack_kernel<<<dim3(64, 16, 8), 256, 0, stream>>>(X, XT);
    main_kernel<<<8192, 256, 0, stream>>>(X, W, ws, XT, out);
}

// Round 9
// 269.255 us; speedup vs baseline: 19.4400x; 1.2086x over previous
//
#include <hip/hip_runtime.h>
#include <hip/hip_bf16.h>

#define N 2048

typedef float f4 __attribute__((ext_vector_type(4)));
typedef unsigned int u32;
typedef u32 u32x4 __attribute__((ext_vector_type(4)));

// ws float offsets
#define OFF_ROWSUM 0
#define OFF_COLSUM 32768
#define OFF_DIAG   65536
#define OFF_SUMS   98304      // [0..15]=diagsum, [16..31]=totsum
#define OFF_A      98336
#define OFF_B      131104
#define OFF_D      163872
#define OFF_C      196640
#define OFF_ROWPART 196656    // 16 panels * 16 c * 2048
#define OFF_COLPART 720944    // 64 slabs  * 16 c * 2048

// ---------------- fused pack + reduce ----------------
// Block = (32-row slab s0, 128-col panel t0, channel-pair cz).
// Stages [2][32][132] tile once; from it produces:
//   XT[cz][t][s] bf16-pair transpose (main's transpose operand)
//   rowpart[panel][c][row], colpart[slab][c][col], diagv[c][i]
// This replaces the separate reduce_kernel -> saves a full 268 MB X read.
__global__ __launch_bounds__(256, 4) void packreduce_kernel(const float* __restrict__ X,
                                                            float* __restrict__ ws,
                                                            u32* __restrict__ XT) {
    const int s0 = blockIdx.x * 32;    // 64 slabs
    const int t0 = blockIdx.y * 128;   // 16 panels
    const int cz = blockIdx.z;         // 8 channel pairs
    const int tid = threadIdx.x;

    __shared__ float lds[2][32][132];

    #pragma unroll
    for (int j = 0; j < 8; ++j) {
        const int idx = tid + 256 * j;           // 0..2047 f4 slots
        const int ch = idx >> 10, row = (idx >> 5) & 31, c4 = idx & 31;
        const f4 v = *(const f4*)(X + (size_t)(2 * cz + ch) * N * N + (size_t)(s0 + row) * N + t0 + 4 * c4);
        *(f4*)&lds[ch][row][4 * c4] = v;
    }
    __syncthreads();

    // XT write: bf16(ch0) | bf16(ch1)<<16, transposed
    #pragma unroll
    for (int j = 0; j < 4; ++j) {
        const int idx = tid + 256 * j;           // 0..1023 u32x4 chunks
        const int tt = idx >> 3, xq = idx & 7;
        u32x4 w;
        #pragma unroll
        for (int i = 0; i < 4; ++i) {
            const int sl = 4 * xq + i;
            const unsigned short lo = __builtin_bit_cast(unsigned short, __float2bfloat16(lds[0][sl][tt]));
            const unsigned short hi = __builtin_bit_cast(unsigned short, __float2bfloat16(lds[1][sl][tt]));
            w[i] = (u32)lo | ((u32)hi << 16);
        }
        __builtin_nontemporal_store(w, (u32x4*)(XT + (size_t)cz * N * N + (size_t)(t0 + tt) * N + s0 + 4 * xq));
    }

    // rowpart: 64 (ch,row) pairs x 4 segments of 32 cols
    {
        const int pr = tid >> 2, seg = tid & 3;
        const int ch = pr >> 5, row = pr & 31;
        float rs = 0.f;
        #pragma unroll
        for (int j = 0; j < 8; ++j) {
            const f4 v = *(const f4*)&lds[ch][row][seg * 32 + 4 * j];
            rs += (v.x + v.y) + (v.z + v.w);
        }
        rs += __shfl_xor(rs, 1);
        rs += __shfl_xor(rs, 2);
        if (seg == 0)
            ws[OFF_ROWPART + (size_t)((t0 >> 7) * 16 + 2 * cz + ch) * N + s0 + row] = rs;
    }

    // colpart: 256 (ch,col) pairs, sum 32 rows
    {
        const int ch = tid >> 7, col = tid & 127;
        float cs = 0.f;
        #pragma unroll
        for (int r = 0; r < 32; ++r) cs += lds[ch][r][col];
        ws[OFF_COLPART + (size_t)((s0 >> 5) * 16 + 2 * cz + ch) * N + t0 + col] = cs;
    }

    // diag: tile rows s0+r hit the diagonal when the column lands in this panel
    if (tid < 64) {
        const int ch = tid >> 5, r = tid & 31;
        const int col = s0 + r - t0;
        if (col >= 0 && col < 128)
            ws[OFF_DIAG + (2 * cz + ch) * N + s0 + r] = lds[ch][r][col];
    }
}

// ---------------- rowcol: combine partials ----------------
__global__ __launch_bounds__(256) void rowcol_kernel(float* __restrict__ ws) {
    const int c = blockIdx.y;
    const int y = blockIdx.x * 256 + threadIdx.x;
    float rs = 0.f;
    #pragma unroll
    for (int p = 0; p < 16; ++p) rs += ws[OFF_ROWPART + (size_t)(p * 16 + c) * N + y];
    ws[OFF_ROWSUM + c * N + y] = rs;
    float cs = 0.f;
    #pragma unroll
    for (int s = 0; s < 64; ++s) cs += ws[OFF_COLPART + (size_t)(s * 16 + c) * N + y];
    ws[OFF_COLSUM + c * N + y] = cs;
}

// ---------------- sums: diagsum / totsum per channel ----------------
__global__ __launch_bounds__(256) void sums_kernel(float* __restrict__ ws) {
    const int c = blockIdx.x;
    const int tid = threadIdx.x;
    float tot = 0.f, dg = 0.f;
    #pragma unroll
    for (int j = 0; j < 8; ++j) {
        tot += ws[OFF_ROWSUM + c * N + tid + 256 * j];
        dg  += ws[OFF_DIAG   + c * N + tid + 256 * j];
    }
    #pragma unroll
    for (int s = 1; s < 64; s <<= 1) { tot += __shfl_xor(tot, s); dg += __shfl_xor(dg, s); }
    __shared__ float buf[2][4];
    const int wave = tid >> 6, lane = tid & 63;
    if (lane == 0) { buf[0][wave] = tot; buf[1][wave] = dg; }
    __syncthreads();
    if (tid == 0) {
        ws[OFF_SUMS + 16 + c] = buf[0][0] + buf[0][1] + buf[0][2] + buf[0][3];
        ws[OFF_SUMS + c]      = buf[1][0] + buf[1][1] + buf[1][2] + buf[1][3];
    }
}

// ---------------- fold: A, B, D, C ----------------
__global__ __launch_bounds__(256) void fold_kernel(const float* __restrict__ W,
                                                   const float* __restrict__ bias,
                                                   float* __restrict__ ws) {
    const int o = blockIdx.y;
    const int x = blockIdx.x * 256 + threadIdx.x;
    const float invN = 1.f / (float)N;
    const float invN2 = invN * invN;
    const float* rowsum = ws + OFF_ROWSUM;
    const float* colsum = ws + OFF_COLSUM;
    const float* diagv  = ws + OFF_DIAG;
    const float* sums   = ws + OFF_SUMS;
    float* Abuf = ws + OFF_A;
    float* Bbuf = ws + OFF_B;
    float* Dbuf = ws + OFF_D;
    float* Cbuf = ws + OFF_C;

    if (blockIdx.x == 0 && threadIdx.x == 0) {
        float cacc = 0.f;
        #pragma unroll
        for (int c = 0; c < 16; ++c)
            cacc += (sums[c] * invN) * W[11 * 256 + c * 16 + o]
                  + (sums[16 + c] * invN2) * W[14 * 256 + c * 16 + o];
        float sb = 0.f;
        for (int p = 0; p < 15; ++p) sb += bias[p];
        Cbuf[o] = cacc + sb;
    }

    // uniform part of D (diagmean, totmean terms)
    float du = 0.f;
    #pragma unroll
    for (int c = 0; c < 16; ++c)
        du += (sums[c] * invN) * W[2 * 256 + c * 16 + o]
            + (sums[16 + c] * invN2) * W[4 * 256 + c * 16 + o];

    float a = 0.f, b = 0.f, d = 0.f;
    #pragma unroll
    for (int c = 0; c < 16; ++c) {
        const float dg = diagv[c * N + x];
        const float rm = rowsum[c * N + x] * invN;
        const float cm = colsum[c * N + x] * invN;
        a += dg * W[5 * 256 + c * 16 + o] + rm * W[12 * 256 + c * 16 + o] + cm * W[7 * 256 + c * 16 + o];
        b += dg * W[9 * 256 + c * 16 + o] + rm * W[13 * 256 + c * 16 + o] + cm * W[10 * 256 + c * 16 + o];
        d += dg * W[0 * 256 + c * 16 + o] + rm * W[3 * 256 + c * 16 + o]  + cm * W[1 * 256 + c * 16 + o];
    }
    Abuf[o * N + x] = a;
    Bbuf[o * N + x] = b;
    Dbuf[o * N + x] = d + du;
}

// ---------------- main: fully-streaming kernel ----------------
// 256 threads: og = tid>>7 (8 outputs), qi = tid&127 -> f4 pixel-quad.
// No LDS tiles. X read 1KB/inst, XT (bf16 pairs) 512B/inst, out 1KB/inst.
// XT lives in out's upper half: slot (c2,x,y) == out slot (8+c2,x,y), so each
// block only reads its OWN pixels' XT; __syncthreads before stores orders
// read-before-overwrite within the block.
__global__ __launch_bounds__(256, 4) void main_kernel(const float* __restrict__ X,
                                                      const float* __restrict__ W,
                                                      const float* __restrict__ ws,
                                                      const u32* __restrict__ XT,
                                                      float* __restrict__ out) {
    const int tid = threadIdx.x;
    const int og = __builtin_amdgcn_readfirstlane(tid >> 7);
    const int qi = tid & 127;
    const size_t p = ((size_t)blockIdx.x * 128 + qi) * 4;   // pixel flat index
    const int x = (int)(p >> 11);
    const int y = (int)(p & 2047);

    const float* Wid = W + 8 * 256 + og * 8;   // identity partition, o-slice
    const float* Wtr = W + 6 * 256 + og * 8;   // transpose partition, o-slice

    f4 acc[8];
    #pragma unroll
    for (int oo = 0; oo < 8; ++oo) acc[oo] = (f4)(0.f);

    #pragma unroll 2
    for (int c2 = 0; c2 < 8; ++c2) {
        const int c0 = 2 * c2;
        const f4 xa = *(const f4*)(X + (size_t)c0 * N * N + p);
        const f4 xb = *(const f4*)(X + (size_t)(c0 + 1) * N * N + p);
        const u32x4 xt = *(const u32x4*)(XT + (size_t)c2 * N * N + p);
        f4 ta, tb;
        #pragma unroll
        for (int i = 0; i < 4; ++i) {
            ta[i] = __builtin_bit_cast(float, xt[i] << 16);
            tb[i] = __builtin_bit_cast(float, xt[i] & 0xffff0000u);
        }
        const f4 wiA0 = *(const f4*)&Wid[c0 * 16];
        const f4 wiA1 = *(const f4*)&Wid[c0 * 16 + 4];
        const f4 wiB0 = *(const f4*)&Wid[c0 * 16 + 16];
        const f4 wiB1 = *(const f4*)&Wid[c0 * 16 + 20];
        const f4 wtA0 = *(const f4*)&Wtr[c0 * 16];
        const f4 wtA1 = *(const f4*)&Wtr[c0 * 16 + 4];
        const f4 wtB0 = *(const f4*)&Wtr[c0 * 16 + 16];
        const f4 wtB1 = *(const f4*)&Wtr[c0 * 16 + 20];
        #pragma unroll
        for (int oo = 0; oo < 4; ++oo) {
            acc[oo]     += wiA0[oo] * xa + wiB0[oo] * xb + wtA0[oo] * ta + wtB0[oo] * tb;
            acc[oo + 4] += wiA1[oo] * xa + wiB1[oo] * xb + wtA1[oo] * ta + wtB1[oo] * tb;
        }
    }

    __syncthreads();   // all XT reads in this block complete before upper-half stores

    const float* Abuf = ws + OFF_A;
    const float* Bbuf = ws + OFF_B;
    const float* Dbuf = ws + OFF_D;
    const float* Cbuf = ws + OFF_C;

    #pragma unroll
    for (int oo = 0; oo < 8; ++oo) {
        const int o = og * 8 + oo;
        const float av = Abuf[o * N + x] + Cbuf[o];
        const f4 bv = *(const f4*)&Bbuf[o * N + y];
        f4 v = acc[oo] + av + bv;
        const int d = x - y;
        if (d >= 0 && d < 4) v[d] += Dbuf[o * N + x];
        __builtin_nontemporal_store(v, (f4*)(out + (size_t)o * N * N + p));
    }
}

extern "C" void kernel_launch(void* const* d_in, const int* in_sizes, int n_in,
                              void* d_out, int out_size, void* d_ws, size_t ws_size,
                              hipStream_t stream) {
    (void)in_sizes; (void)n_in; (void)out_size; (void)ws_size;
    const float* X    = (const float*)d_in[0];
    const float* W    = (const float*)d_in[1];
    const float* bias = (const float*)d_in[2];
    float* out = (float*)d_out;
    float* ws  = (float*)d_ws;
    u32* XT = (u32*)(out + (size_t)8 * N * N);   // upper half of d_out as scratch

    packreduce_kernel<<<dim3(64, 16, 8), 256, 0, stream>>>(X, ws, XT);
    rowcol_kernel<<<dim3(8, 16), 256, 0, stream>>>(ws);
    sums_kernel<<<16, 256, 0, stream>>>(ws);
    fold_kernel<<<dim3(8, 16), 256, 0, stream>>>(W, bias, ws);
    main_kernel<<<8192, 256, 0, stream>>>(X, W, ws, XT, out);
}

// Round 10
// 248.981 us; speedup vs baseline: 21.0229x; 1.0814x over previous
//
#include <hip/hip_runtime.h>
#include <hip/hip_bf16.h>

#define N 2048

typedef float f4 __attribute__((ext_vector_type(4)));
typedef unsigned int u32;
typedef u32 u32x4 __attribute__((ext_vector_type(4)));

// ws float offsets
#define OFF_ROWSUM 0
#define OFF_COLSUM 32768
#define OFF_DIAG   65536
#define OFF_SUMS   98304      // [0..15]=diagsum, [16..31]=totsum
#define OFF_A      98336
#define OFF_B      131104
#define OFF_D      163872
#define OFF_C      196640
#define OFF_ROWPART 196656    // 16 panels * 16 c * 2048
#define OFF_COLPART 720944    // 64 slabs  * 16 c * 2048

// ---------------- fused pack + reduce ----------------
// Block = (32-row slab s0, 128-col panel t0, channel-pair cz).
// Stages [2][32][132] tile once; from it produces:
//   XT[cz][t][s] bf16-pair transpose (main's transpose operand) -- NOT
//   nontemporal: XT (134 MB) fits in L3 and main re-reads it shortly.
//   rowpart[panel][c][row], colpart[slab][c][col], diagv[c][i]
__global__ __launch_bounds__(256, 4) void packreduce_kernel(const float* __restrict__ X,
                                                            float* __restrict__ ws,
                                                            u32* __restrict__ XT) {
    const int s0 = blockIdx.x * 32;    // 64 slabs
    const int t0 = blockIdx.y * 128;   // 16 panels
    const int cz = blockIdx.z;         // 8 channel pairs
    const int tid = threadIdx.x;

    __shared__ float lds[2][32][132];

    #pragma unroll
    for (int j = 0; j < 8; ++j) {
        const int idx = tid + 256 * j;           // 0..2047 f4 slots
        const int ch = idx >> 10, row = (idx >> 5) & 31, c4 = idx & 31;
        const f4 v = *(const f4*)(X + (size_t)(2 * cz + ch) * N * N + (size_t)(s0 + row) * N + t0 + 4 * c4);
        *(f4*)&lds[ch][row][4 * c4] = v;
    }
    __syncthreads();

    // XT write: bf16(ch0) | bf16(ch1)<<16, transposed
    #pragma unroll
    for (int j = 0; j < 4; ++j) {
        const int idx = tid + 256 * j;           // 0..1023 u32x4 chunks
        const int tt = idx >> 3, xq = idx & 7;
        u32x4 w;
        #pragma unroll
        for (int i = 0; i < 4; ++i) {
            const int sl = 4 * xq + i;
            const unsigned short lo = __builtin_bit_cast(unsigned short, __float2bfloat16(lds[0][sl][tt]));
            const unsigned short hi = __builtin_bit_cast(unsigned short, __float2bfloat16(lds[1][sl][tt]));
            w[i] = (u32)lo | ((u32)hi << 16);
        }
        *(u32x4*)(XT + (size_t)cz * N * N + (size_t)(t0 + tt) * N + s0 + 4 * xq) = w;
    }

    // rowpart: 64 (ch,row) pairs x 4 segments of 32 cols
    {
        const int pr = tid >> 2, seg = tid & 3;
        const int ch = pr >> 5, row = pr & 31;
        float rs = 0.f;
        #pragma unroll
        for (int j = 0; j < 8; ++j) {
            const f4 v = *(const f4*)&lds[ch][row][seg * 32 + 4 * j];
            rs += (v.x + v.y) + (v.z + v.w);
        }
        rs += __shfl_xor(rs, 1);
        rs += __shfl_xor(rs, 2);
        if (seg == 0)
            ws[OFF_ROWPART + (size_t)((t0 >> 7) * 16 + 2 * cz + ch) * N + s0 + row] = rs;
    }

    // colpart: 256 (ch,col) pairs, sum 32 rows
    {
        const int ch = tid >> 7, col = tid & 127;
        float cs = 0.f;
        #pragma unroll
        for (int r = 0; r < 32; ++r) cs += lds[ch][r][col];
        ws[OFF_COLPART + (size_t)((s0 >> 5) * 16 + 2 * cz + ch) * N + t0 + col] = cs;
    }

    // diag: tile rows s0+r hit the diagonal when the column lands in this panel
    if (tid < 64) {
        const int ch = tid >> 5, r = tid & 31;
        const int col = s0 + r - t0;
        if (col >= 0 && col < 128)
            ws[OFF_DIAG + (2 * cz + ch) * N + s0 + r] = lds[ch][r][col];
    }
}

// ---------------- rowcolsums: combine partials + per-channel sums ----------------
__global__ __launch_bounds__(256) void rowcolsums_kernel(float* __restrict__ ws) {
    const int c = blockIdx.y;
    const int tid = threadIdx.x;
    const int y = blockIdx.x * 256 + tid;
    float rs = 0.f;
    #pragma unroll
    for (int p = 0; p < 16; ++p) rs += ws[OFF_ROWPART + (size_t)(p * 16 + c) * N + y];
    ws[OFF_ROWSUM + c * N + y] = rs;
    float cs = 0.f;
    #pragma unroll
    for (int s = 0; s < 64; ++s) cs += ws[OFF_COLPART + (size_t)(s * 16 + c) * N + y];
    ws[OFF_COLSUM + c * N + y] = cs;

    if (blockIdx.x == 0) {
        // totsum from rowpart (16 panels x 2048), diagsum from diag
        float tot = 0.f, dg = 0.f;
        for (int p = 0; p < 16; ++p)
            #pragma unroll
            for (int j = 0; j < 8; ++j)
                tot += ws[OFF_ROWPART + (size_t)(p * 16 + c) * N + tid + 256 * j];
        #pragma unroll
        for (int j = 0; j < 8; ++j)
            dg += ws[OFF_DIAG + c * N + tid + 256 * j];
        #pragma unroll
        for (int s = 1; s < 64; s <<= 1) { tot += __shfl_xor(tot, s); dg += __shfl_xor(dg, s); }
        __shared__ float buf[2][4];
        const int wave = tid >> 6, lane = tid & 63;
        if (lane == 0) { buf[0][wave] = tot; buf[1][wave] = dg; }
        __syncthreads();
        if (tid == 0) {
            ws[OFF_SUMS + 16 + c] = buf[0][0] + buf[0][1] + buf[0][2] + buf[0][3];
            ws[OFF_SUMS + c]      = buf[1][0] + buf[1][1] + buf[1][2] + buf[1][3];
        }
    }
}

// ---------------- fold: A, B, D, C ----------------
__global__ __launch_bounds__(256) void fold_kernel(const float* __restrict__ W,
                                                   const float* __restrict__ bias,
                                                   float* __restrict__ ws) {
    const int o = blockIdx.y;
    const int x = blockIdx.x * 256 + threadIdx.x;
    const float invN = 1.f / (float)N;
    const float invN2 = invN * invN;
    const float* rowsum = ws + OFF_ROWSUM;
    const float* colsum = ws + OFF_COLSUM;
    const float* diagv  = ws + OFF_DIAG;
    const float* sums   = ws + OFF_SUMS;
    float* Abuf = ws + OFF_A;
    float* Bbuf = ws + OFF_B;
    float* Dbuf = ws + OFF_D;
    float* Cbuf = ws + OFF_C;

    if (blockIdx.x == 0 && threadIdx.x == 0) {
        float cacc = 0.f;
        #pragma unroll
        for (int c = 0; c < 16; ++c)
            cacc += (sums[c] * invN) * W[11 * 256 + c * 16 + o]
                  + (sums[16 + c] * invN2) * W[14 * 256 + c * 16 + o];
        float sb = 0.f;
        for (int p = 0; p < 15; ++p) sb += bias[p];
        Cbuf[o] = cacc + sb;
    }

    // uniform part of D (diagmean, totmean terms)
    float du = 0.f;
    #pragma unroll
    for (int c = 0; c < 16; ++c)
        du += (sums[c] * invN) * W[2 * 256 + c * 16 + o]
            + (sums[16 + c] * invN2) * W[4 * 256 + c * 16 + o];

    float a = 0.f, b = 0.f, d = 0.f;
    #pragma unroll
    for (int c = 0; c < 16; ++c) {
        const float dg = diagv[c * N + x];
        const float rm = rowsum[c * N + x] * invN;
        const float cm = colsum[c * N + x] * invN;
        a += dg * W[5 * 256 + c * 16 + o] + rm * W[12 * 256 + c * 16 + o] + cm * W[7 * 256 + c * 16 + o];
        b += dg * W[9 * 256 + c * 16 + o] + rm * W[13 * 256 + c * 16 + o] + cm * W[10 * 256 + c * 16 + o];
        d += dg * W[0 * 256 + c * 16 + o] + rm * W[3 * 256 + c * 16 + o]  + cm * W[1 * 256 + c * 16 + o];
    }
    Abuf[o * N + x] = a;
    Bbuf[o * N + x] = b;
    Dbuf[o * N + x] = d + du;
}

// ---------------- main: fully-streaming kernel ----------------
// 256 threads: og = tid>>7 (8 outputs), qi = tid&127 -> f4 pixel-quad.
// No LDS tiles. X read 1KB/inst, XT (bf16 pairs) 512B/inst, out 1KB/inst.
// XT lives in out's upper half: slot (c2,x,y) == out slot (8+c2,x,y), so each
// block only reads its OWN pixels' XT; __syncthreads before stores orders
// read-before-overwrite within the block.
__global__ __launch_bounds__(256, 4) void main_kernel(const float* __restrict__ X,
                                                      const float* __restrict__ W,
                                                      const float* __restrict__ ws,
                                                      const u32* __restrict__ XT,
                                                      float* __restrict__ out) {
    const int tid = threadIdx.x;
    const int og = __builtin_amdgcn_readfirstlane(tid >> 7);
    const int qi = tid & 127;
    const size_t p = ((size_t)blockIdx.x * 128 + qi) * 4;   // pixel flat index
    const int x = (int)(p >> 11);
    const int y = (int)(p & 2047);

    const float* Wid = W + 8 * 256 + og * 8;   // identity partition, o-slice
    const float* Wtr = W + 6 * 256 + og * 8;   // transpose partition, o-slice

    f4 acc[8];
    #pragma unroll
    for (int oo = 0; oo < 8; ++oo) acc[oo] = (f4)(0.f);

    #pragma unroll 4
    for (int c2 = 0; c2 < 8; ++c2) {
        const int c0 = 2 * c2;
        const f4 xa = *(const f4*)(X + (size_t)c0 * N * N + p);
        const f4 xb = *(const f4*)(X + (size_t)(c0 + 1) * N * N + p);
        const u32x4 xt = *(const u32x4*)(XT + (size_t)c2 * N * N + p);
        f4 ta, tb;
        #pragma unroll
        for (int i = 0; i < 4; ++i) {
            ta[i] = __builtin_bit_cast(float, xt[i] << 16);
            tb[i] = __builtin_bit_cast(float, xt[i] & 0xffff0000u);
        }
        const f4 wiA0 = *(const f4*)&Wid[c0 * 16];
        const f4 wiA1 = *(const f4*)&Wid[c0 * 16 + 4];
        const f4 wiB0 = *(const f4*)&Wid[c0 * 16 + 16];
        const f4 wiB1 = *(const f4*)&Wid[c0 * 16 + 20];
        const f4 wtA0 = *(const f4*)&Wtr[c0 * 16];
        const f4 wtA1 = *(const f4*)&Wtr[c0 * 16 + 4];
        const f4 wtB0 = *(const f4*)&Wtr[c0 * 16 + 16];
        const f4 wtB1 = *(const f4*)&Wtr[c0 * 16 + 20];
        #pragma unroll
        for (int oo = 0; oo < 4; ++oo) {
            acc[oo]     += wiA0[oo] * xa + wiB0[oo] * xb + wtA0[oo] * ta + wtB0[oo] * tb;
            acc[oo + 4] += wiA1[oo] * xa + wiB1[oo] * xb + wtA1[oo] * ta + wtB1[oo] * tb;
        }
    }

    __syncthreads();   // all XT reads in this block complete before upper-half stores

    const float* Abuf = ws + OFF_A;
    const float* Bbuf = ws + OFF_B;
    const float* Dbuf = ws + OFF_D;
    const float* Cbuf = ws + OFF_C;

    #pragma unroll
    for (int oo = 0; oo < 8; ++oo) {
        const int o = og * 8 + oo;
        const float av = Abuf[o * N + x] + Cbuf[o];
        const f4 bv = *(const f4*)&Bbuf[o * N + y];
        f4 v = acc[oo] + av + bv;
        const int d = x - y;
        if (d >= 0 && d < 4) v[d] += Dbuf[o * N + x];
        __builtin_nontemporal_store(v, (f4*)(out + (size_t)o * N * N + p));
    }
}

extern "C" void kernel_launch(void* const* d_in, const int* in_sizes, int n_in,
                              void* d_out, int out_size, void* d_ws, size_t ws_size,
                              hipStream_t stream) {
    (void)in_sizes; (void)n_in; (void)out_size; (void)ws_size;
    const float* X    = (const float*)d_in[0];
    const float* W    = (const float*)d_in[1];
    const float* bias = (const float*)d_in[2];
    float* out = (float*)d_out;
    float* ws  = (float*)d_ws;
    u32* XT = (u32*)(out + (size_t)8 * N * N);   // upper half of d_out as scratch

    packreduce_kernel<<<dim3(64, 16, 8), 256, 0, stream>>>(X, ws, XT);
    rowcolsums_kernel<<<dim3(8, 16), 256, 0, stream>>>(ws);
    fold_kernel<<<dim3(8, 16), 256, 0, stream>>>(W, bias, ws);
    main_kernel<<<8192, 256, 0, stream>>>(X, W, ws, XT, out);
}

// Round 11
// 230.107 us; speedup vs baseline: 22.7473x; 1.0820x over previous
//
#include <hip/hip_runtime.h>
#include <hip/hip_bf16.h>

#define N 2048

typedef float f4 __attribute__((ext_vector_type(4)));
typedef unsigned int u32;
typedef u32 u32x4 __attribute__((ext_vector_type(4)));

// ws float offsets
#define OFF_ROWSUM 0
#define OFF_COLSUM 32768
#define OFF_DIAG   65536
#define OFF_SUMS   98304      // [0..15]=diagsum, [16..31]=totsum
#define OFF_A      98336
#define OFF_B      131104
#define OFF_D      163872
#define OFF_C      196640
#define OFF_ROWPART 196656    // 16 panels * 16 c * 2048
#define OFF_COLPART 720944    // 64 slabs  * 16 c * 2048

// ---------------- fused pack + reduce ----------------
// Block = (32-row slab s0, 128-col panel t0, channel-pair cz).
// Stages [2][32][132] f32 tile once; produces:
//   XD[cz][x][y]  bf16-pair DIRECT copy   (-> out channels 0..7)
//   XT[cz][t][s]  bf16-pair TRANSPOSE     (-> out channels 8..15)
//   rowpart / colpart / diag partials (f32, from the staged tile)
// XD removes main's 268 MB f32 X re-read; both packs stay L3-warm for main.
__global__ __launch_bounds__(256, 4) void packreduce_kernel(const float* __restrict__ X,
                                                            float* __restrict__ ws,
                                                            u32* __restrict__ XD,
                                                            u32* __restrict__ XT) {
    const int s0 = blockIdx.x * 32;    // 64 slabs
    const int t0 = blockIdx.y * 128;   // 16 panels
    const int cz = blockIdx.z;         // 8 channel pairs
    const int tid = threadIdx.x;

    __shared__ float lds[2][32][132];

    // staging + XD: 1024 (row,c4) quads; each thread loads both channels of one quad
    #pragma unroll
    for (int j = 0; j < 4; ++j) {
        const int idx = tid + 256 * j;           // 0..1023
        const int row = idx >> 5, c4 = idx & 31;
        const float* src = X + (size_t)(2 * cz) * N * N + (size_t)(s0 + row) * N + t0 + 4 * c4;
        const f4 v0 = *(const f4*)src;
        const f4 v1 = *(const f4*)(src + N * N);
        *(f4*)&lds[0][row][4 * c4] = v0;
        *(f4*)&lds[1][row][4 * c4] = v1;
        u32x4 wd;
        #pragma unroll
        for (int i = 0; i < 4; ++i) {
            const unsigned short lo = __builtin_bit_cast(unsigned short, __float2bfloat16(v0[i]));
            const unsigned short hi = __builtin_bit_cast(unsigned short, __float2bfloat16(v1[i]));
            wd[i] = (u32)lo | ((u32)hi << 16);
        }
        *(u32x4*)(XD + (size_t)cz * N * N + (size_t)(s0 + row) * N + t0 + 4 * c4) = wd;
    }
    __syncthreads();

    // XT write: bf16(ch0) | bf16(ch1)<<16, transposed
    #pragma unroll
    for (int j = 0; j < 4; ++j) {
        const int idx = tid + 256 * j;           // 0..1023 u32x4 chunks
        const int tt = idx >> 3, xq = idx & 7;
        u32x4 w;
        #pragma unroll
        for (int i = 0; i < 4; ++i) {
            const int sl = 4 * xq + i;
            const unsigned short lo = __builtin_bit_cast(unsigned short, __float2bfloat16(lds[0][sl][tt]));
            const unsigned short hi = __builtin_bit_cast(unsigned short, __float2bfloat16(lds[1][sl][tt]));
            w[i] = (u32)lo | ((u32)hi << 16);
        }
        *(u32x4*)(XT + (size_t)cz * N * N + (size_t)(t0 + tt) * N + s0 + 4 * xq) = w;
    }

    // rowpart: 64 (ch,row) pairs x 4 segments of 32 cols
    {
        const int pr = tid >> 2, seg = tid & 3;
        const int ch = pr >> 5, row = pr & 31;
        float rs = 0.f;
        #pragma unroll
        for (int j = 0; j < 8; ++j) {
            const f4 v = *(const f4*)&lds[ch][row][seg * 32 + 4 * j];
            rs += (v.x + v.y) + (v.z + v.w);
        }
        rs += __shfl_xor(rs, 1);
        rs += __shfl_xor(rs, 2);
        if (seg == 0)
            ws[OFF_ROWPART + (size_t)((t0 >> 7) * 16 + 2 * cz + ch) * N + s0 + row] = rs;
    }

    // colpart: 256 (ch,col) pairs, sum 32 rows
    {
        const int ch = tid >> 7, col = tid & 127;
        float cs = 0.f;
        #pragma unroll
        for (int r = 0; r < 32; ++r) cs += lds[ch][r][col];
        ws[OFF_COLPART + (size_t)((s0 >> 5) * 16 + 2 * cz + ch) * N + t0 + col] = cs;
    }

    // diag: tile rows s0+r hit the diagonal when the column lands in this panel
    if (tid < 64) {
        const int ch = tid >> 5, r = tid & 31;
        const int col = s0 + r - t0;
        if (col >= 0 && col < 128)
            ws[OFF_DIAG + (2 * cz + ch) * N + s0 + r] = lds[ch][r][col];
    }
}

// ---------------- rowcolsums: combine partials + per-channel sums ----------------
__global__ __launch_bounds__(256) void rowcolsums_kernel(float* __restrict__ ws) {
    const int c = blockIdx.y;
    const int tid = threadIdx.x;
    const int y = blockIdx.x * 256 + tid;
    float rs = 0.f;
    #pragma unroll
    for (int p = 0; p < 16; ++p) rs += ws[OFF_ROWPART + (size_t)(p * 16 + c) * N + y];
    ws[OFF_ROWSUM + c * N + y] = rs;
    float cs = 0.f;
    #pragma unroll
    for (int s = 0; s < 64; ++s) cs += ws[OFF_COLPART + (size_t)(s * 16 + c) * N + y];
    ws[OFF_COLSUM + c * N + y] = cs;

    if (blockIdx.x == 0) {
        float tot = 0.f, dg = 0.f;
        for (int p = 0; p < 16; ++p)
            #pragma unroll
            for (int j = 0; j < 8; ++j)
                tot += ws[OFF_ROWPART + (size_t)(p * 16 + c) * N + tid + 256 * j];
        #pragma unroll
        for (int j = 0; j < 8; ++j)
            dg += ws[OFF_DIAG + c * N + tid + 256 * j];
        #pragma unroll
        for (int s = 1; s < 64; s <<= 1) { tot += __shfl_xor(tot, s); dg += __shfl_xor(dg, s); }
        __shared__ float buf[2][4];
        const int wave = tid >> 6, lane = tid & 63;
        if (lane == 0) { buf[0][wave] = tot; buf[1][wave] = dg; }
        __syncthreads();
        if (tid == 0) {
            ws[OFF_SUMS + 16 + c] = buf[0][0] + buf[0][1] + buf[0][2] + buf[0][3];
            ws[OFF_SUMS + c]      = buf[1][0] + buf[1][1] + buf[1][2] + buf[1][3];
        }
    }
}

// ---------------- fold: A, B, D, C ----------------
__global__ __launch_bounds__(256) void fold_kernel(const float* __restrict__ W,
                                                   const float* __restrict__ bias,
                                                   float* __restrict__ ws) {
    const int o = blockIdx.y;
    const int x = blockIdx.x * 256 + threadIdx.x;
    const float invN = 1.f / (float)N;
    const float invN2 = invN * invN;
    const float* rowsum = ws + OFF_ROWSUM;
    const float* colsum = ws + OFF_COLSUM;
    const float* diagv  = ws + OFF_DIAG;
    const float* sums   = ws + OFF_SUMS;
    float* Abuf = ws + OFF_A;
    float* Bbuf = ws + OFF_B;
    float* Dbuf = ws + OFF_D;
    float* Cbuf = ws + OFF_C;

    if (blockIdx.x == 0 && threadIdx.x == 0) {
        float cacc = 0.f;
        #pragma unroll
        for (int c = 0; c < 16; ++c)
            cacc += (sums[c] * invN) * W[11 * 256 + c * 16 + o]
                  + (sums[16 + c] * invN2) * W[14 * 256 + c * 16 + o];
        float sb = 0.f;
        for (int p = 0; p < 15; ++p) sb += bias[p];
        Cbuf[o] = cacc + sb;
    }

    float du = 0.f;
    #pragma unroll
    for (int c = 0; c < 16; ++c)
        du += (sums[c] * invN) * W[2 * 256 + c * 16 + o]
            + (sums[16 + c] * invN2) * W[4 * 256 + c * 16 + o];

    float a = 0.f, b = 0.f, d = 0.f;
    #pragma unroll
    for (int c = 0; c < 16; ++c) {
        const float dg = diagv[c * N + x];
        const float rm = rowsum[c * N + x] * invN;
        const float cm = colsum[c * N + x] * invN;
        a += dg * W[5 * 256 + c * 16 + o] + rm * W[12 * 256 + c * 16 + o] + cm * W[7 * 256 + c * 16 + o];
        b += dg * W[9 * 256 + c * 16 + o] + rm * W[13 * 256 + c * 16 + o] + cm * W[10 * 256 + c * 16 + o];
        d += dg * W[0 * 256 + c * 16 + o] + rm * W[3 * 256 + c * 16 + o]  + cm * W[1 * 256 + c * 16 + o];
    }
    Abuf[o * N + x] = a;
    Bbuf[o * N + x] = b;
    Dbuf[o * N + x] = d + du;
}

// ---------------- main: fully-streaming, all-bf16 inputs ----------------
// 256 threads: og = tid>>7 (8 outputs), qi = tid&127 -> f4 pixel-quad.
// Reads ONLY XD+XT (bf16 pairs, 268 MB total, freshly written -> L3-warm).
// XD = out channels 0..7, XT = channels 8..15: each block reads its own
// pixels' packs, __syncthreads, then overwrites them with the real output.
// Regular (cached) stores so the overwrite kills XD/XT dirty lines in L3.
__global__ __launch_bounds__(256, 4) void main_kernel(const float* __restrict__ W,
                                                      const float* __restrict__ ws,
                                                      const u32* __restrict__ XD,
                                                      const u32* __restrict__ XT,
                                                      float* __restrict__ out) {
    const int tid = threadIdx.x;
    const int og = __builtin_amdgcn_readfirstlane(tid >> 7);
    const int qi = tid & 127;
    const size_t p = ((size_t)blockIdx.x * 128 + qi) * 4;   // pixel flat index
    const int x = (int)(p >> 11);
    const int y = (int)(p & 2047);

    const float* Wid = W + 8 * 256 + og * 8;   // identity partition, o-slice
    const float* Wtr = W + 6 * 256 + og * 8;   // transpose partition, o-slice

    f4 acc[8];
    #pragma unroll
    for (int oo = 0; oo < 8; ++oo) acc[oo] = (f4)(0.f);

    #pragma unroll 4
    for (int c2 = 0; c2 < 8; ++c2) {
        const int c0 = 2 * c2;
        const u32x4 xd = *(const u32x4*)(XD + (size_t)c2 * N * N + p);
        const u32x4 xt = *(const u32x4*)(XT + (size_t)c2 * N * N + p);
        f4 xa, xb, ta, tb;
        #pragma unroll
        for (int i = 0; i < 4; ++i) {
            xa[i] = __builtin_bit_cast(float, xd[i] << 16);
            xb[i] = __builtin_bit_cast(float, xd[i] & 0xffff0000u);
            ta[i] = __builtin_bit_cast(float, xt[i] << 16);
            tb[i] = __builtin_bit_cast(float, xt[i] & 0xffff0000u);
        }
        const f4 wiA0 = *(const f4*)&Wid[c0 * 16];
        const f4 wiA1 = *(const f4*)&Wid[c0 * 16 + 4];
        const f4 wiB0 = *(const f4*)&Wid[c0 * 16 + 16];
        const f4 wiB1 = *(const f4*)&Wid[c0 * 16 + 20];
        const f4 wtA0 = *(const f4*)&Wtr[c0 * 16];
        const f4 wtA1 = *(const f4*)&Wtr[c0 * 16 + 4];
        const f4 wtB0 = *(const f4*)&Wtr[c0 * 16 + 16];
        const f4 wtB1 = *(const f4*)&Wtr[c0 * 16 + 20];
        #pragma unroll
        for (int oo = 0; oo < 4; ++oo) {
            acc[oo]     += wiA0[oo] * xa + wiB0[oo] * xb + wtA0[oo] * ta + wtB0[oo] * tb;
            acc[oo + 4] += wiA1[oo] * xa + wiB1[oo] * xb + wtA1[oo] * ta + wtB1[oo] * tb;
        }
    }

    __syncthreads();   // all XD/XT reads in this block complete before overwrite

    const float* Abuf = ws + OFF_A;
    const float* Bbuf = ws + OFF_B;
    const float* Dbuf = ws + OFF_D;
    const float* Cbuf = ws + OFF_C;

    #pragma unroll
    for (int oo = 0; oo < 8; ++oo) {
        const int o = og * 8 + oo;
        const float av = Abuf[o * N + x] + Cbuf[o];
        const f4 bv = *(const f4*)&Bbuf[o * N + y];
        f4 v = acc[oo] + av + bv;
        const int d = x - y;
        if (d >= 0 && d < 4) v[d] += Dbuf[o * N + x];
        *(f4*)(out + (size_t)o * N * N + p) = v;
    }
}

extern "C" void kernel_launch(void* const* d_in, const int* in_sizes, int n_in,
                              void* d_out, int out_size, void* d_ws, size_t ws_size,
                              hipStream_t stream) {
    (void)in_sizes; (void)n_in; (void)out_size; (void)ws_size;
    const float* X    = (const float*)d_in[0];
    const float* W    = (const float*)d_in[1];
    const float* bias = (const float*)d_in[2];
    float* out = (float*)d_out;
    float* ws  = (float*)d_ws;
    u32* XD = (u32*)out;                          // out channels 0..7
    u32* XT = (u32*)(out + (size_t)8 * N * N);    // out channels 8..15

    packreduce_kernel<<<dim3(64, 16, 8), 256, 0, stream>>>(X, ws, XD, XT);
    rowcolsums_kernel<<<dim3(8, 16), 256, 0, stream>>>(ws);
    fold_kernel<<<dim3(8, 16), 256, 0, stream>>>(W, bias, ws);
    main_kernel<<<8192, 256, 0, stream>>>(W, ws, XD, XT, out);
}